// Round 8
// baseline (390.267 us; speedup 1.0000x reference)
//
#include <hip/hip_runtime.h>
#include <hip/hip_bf16.h>

// ---------------- problem constants ----------------
namespace {
constexpr int Bb = 128, Nn = 12800, Ee = 262144;
constexpr int LAT = 256, HID = 128, FCH = 512, NRBF = 16;
constexpr int TE = 64; // edges per block in edge kernel (divides 2048 = edges/graph)

// workspace offsets (floats)
constexpr int WS_L      = 0;        // B*9
constexpr int WS_LI     = 1152;     // B*9
constexpr int WS_SIG    = 2304;     // B
constexpr int WS_RBFW2  = 2432;     // 16*128
constexpr int WS_CVEC   = 4480;     // 128
constexpr int WS_HB     = 4608;     // 100*128
constexpr int WS_LATP   = 17408;    // B*512
constexpr int WS_PERT   = 82944;    // N*3
constexpr int WS_ALIGN  = 121344;   // N*3
constexpr int WS_SN     = 159744;   // N*3 (atomic)
constexpr int WS_GN     = 198144;   // N*3 (atomic)
constexpr int WS_PREDS  = 236544;   // N*3
constexpr int WS_BSUM   = 274944;   // B*3 (atomic)
constexpr int WS_CENTER = 275328;   // B*3 (atomic)
constexpr int WS_MINMAX = 275712;   // 6   (max x3, min x3)
// bf16 fragment-tiled weights (stored as ushort), float-index base:
constexpr int WS_W0T_F  = 276000;   // ushort[512*128]  (= 32768 floats)
constexpr int WS_W1T_F  = 308768;   // ushort[512*512]  (= 131072 floats)
}

typedef short bf16x8 __attribute__((ext_vector_type(8)));
typedef float f32x4 __attribute__((ext_vector_type(4)));

static __device__ __forceinline__ unsigned short f2bf(float f) {
  unsigned int u = __float_as_uint(f);
  unsigned int r = (u + 0x7fffu + ((u >> 16) & 1u)) >> 16;
  return (unsigned short)r;
}
// packed pair: returns uint with bf16(a) in low16, bf16(b) in high16
static __device__ __forceinline__ unsigned int pk2bf(float a, float b) {
  __hip_bfloat162 h2 = __float22bfloat162_rn(make_float2(a, b));
  return *reinterpret_cast<unsigned int*>(&h2);
}

static __device__ __forceinline__ void atomicMaxFloat(float* addr, float val) {
  int* ai = reinterpret_cast<int*>(addr);
  int old = *ai;
  while (__int_as_float(old) < val) {
    int assumed = old;
    old = atomicCAS(ai, assumed, __float_as_int(val));
    if (old == assumed) break;
  }
}
static __device__ __forceinline__ void atomicMinFloat(float* addr, float val) {
  int* ai = reinterpret_cast<int*>(addr);
  int old = *ai;
  while (__int_as_float(old) > val) {
    int assumed = old;
    old = atomicCAS(ai, assumed, __float_as_int(val));
    if (old == assumed) break;
  }
}

// ---------------- fused prologue: all mutually-independent prep work ----------------
__global__ __launch_bounds__(256) void k_pre(
    const float* lengths, const float* angles, const float* sigmas, const int* tsteps,
    const float* aemb, const float* bbW, const float* rbfW, const float* rbfb,
    const float* bbb, const float* latents, const float* scW0, const float* scb0,
    const float* scW1, unsigned short* w0t, unsigned short* w1t, float* ws) {
  const int blk = blockIdx.x, t = threadIdx.x;
  if (blk < 304) {
    int gid = blk * 256 + t;
    if (gid < 2 * Nn * 3) ws[WS_SN + gid] = 0.f;
    else if (gid < 2 * Nn * 3 + 2 * Bb * 3) ws[WS_BSUM + (gid - 2 * Nn * 3)] = 0.f;
    else if (gid < 2 * Nn * 3 + 2 * Bb * 3 + 3) ws[WS_MINMAX + (gid - 2 * Nn * 3 - 2 * Bb * 3)] = -3.0e38f;
    else if (gid < 2 * Nn * 3 + 2 * Bb * 3 + 6) ws[WS_MINMAX + (gid - 2 * Nn * 3 - 2 * Bb * 3)] = 3.0e38f;
  } else if (blk == 304) {
    int b = t;
    if (b >= Bb) return;
    float a = lengths[b * 3 + 0], bl = lengths[b * 3 + 1], c = lengths[b * 3 + 2];
    const float d2r = 0.017453292519943295f;
    float al = angles[b * 3 + 0] * d2r, be = angles[b * 3 + 1] * d2r, ga = angles[b * 3 + 2] * d2r;
    float ca = cosf(al), cb = cosf(be), cg = cosf(ga), sa = sinf(al), sb = sinf(be);
    float val = (ca * cb - cg) / (sa * sb);
    val = fminf(1.f, fmaxf(-1.f, val));
    float gs = acosf(val);
    float L[3][3];
    L[0][0] = a * sb;              L[0][1] = 0.f;                L[0][2] = a * cb;
    L[1][0] = -bl * sa * cosf(gs); L[1][1] = bl * sa * sinf(gs); L[1][2] = bl * ca;
    L[2][0] = 0.f;                 L[2][1] = 0.f;                L[2][2] = c;
    float det = L[0][0] * (L[1][1] * L[2][2] - L[1][2] * L[2][1])
              - L[0][1] * (L[1][0] * L[2][2] - L[1][2] * L[2][0])
              + L[0][2] * (L[1][0] * L[2][1] - L[1][1] * L[2][0]);
    float id = 1.f / det;
    float inv[3][3];
    inv[0][0] =  (L[1][1]*L[2][2] - L[1][2]*L[2][1]) * id;
    inv[0][1] = -(L[0][1]*L[2][2] - L[0][2]*L[2][1]) * id;
    inv[0][2] =  (L[0][1]*L[1][2] - L[0][2]*L[1][1]) * id;
    inv[1][0] = -(L[1][0]*L[2][2] - L[1][2]*L[2][0]) * id;
    inv[1][1] =  (L[0][0]*L[2][2] - L[0][2]*L[2][0]) * id;
    inv[1][2] = -(L[0][0]*L[1][2] - L[0][2]*L[1][0]) * id;
    inv[2][0] =  (L[1][0]*L[2][1] - L[1][1]*L[2][0]) * id;
    inv[2][1] = -(L[0][0]*L[2][1] - L[0][1]*L[2][0]) * id;
    inv[2][2] =  (L[0][0]*L[1][1] - L[0][1]*L[1][0]) * id;
    for (int i = 0; i < 3; ++i)
      for (int j = 0; j < 3; ++j) {
        ws[WS_L + b * 9 + i * 3 + j] = L[i][j];
        ws[WS_LI + b * 9 + i * 3 + j] = inv[i][j];
      }
    ws[WS_SIG + b] = sigmas[tsteps[b]];
  } else if (blk < 405) {
    int tile = blk - 305;
    if (t < HID) {
      float acc = 0.f;
      for (int k = 0; k < HID; ++k) acc += aemb[tile * HID + k] * bbW[k * HID + t];
      ws[WS_HB + tile * HID + t] = acc;
    }
  } else if (blk == 405) {
    if (t < HID) {
      float accs[NRBF];
#pragma unroll
      for (int k = 0; k < NRBF; ++k) accs[k] = 0.f;
      float accb = 0.f;
      for (int m = 0; m < HID; ++m) {
        float w = bbW[m * HID + t];
#pragma unroll
        for (int k = 0; k < NRBF; ++k) accs[k] += rbfW[k * HID + m] * w;
        accb += rbfb[m] * w;
      }
#pragma unroll
      for (int k = 0; k < NRBF; ++k) ws[WS_RBFW2 + k * HID + t] = accs[k];
      ws[WS_CVEC + t] = accb + bbb[t];
    }
  } else if (blk < 534) {
    int b = blk - 406;
    __shared__ float lat[LAT];
    lat[t] = latents[b * LAT + t];
    __syncthreads();
    int c0 = 2 * t;
    float a0 = 0.f, a1 = 0.f;
    for (int m = 0; m < LAT; ++m) {
      float2 w = *reinterpret_cast<const float2*>(scW0 + (HID + m) * FCH + c0);
      float lm = lat[m];
      a0 += lm * w.x;
      a1 += lm * w.y;
    }
    ws[WS_LATP + b * FCH + c0] = a0 + scb0[c0];
    ws[WS_LATP + b * FCH + c0 + 1] = a1 + scb0[c0 + 1];
  } else if (blk < 790) {
    int id = (blk - 534) * 256 + t;   // 65536
    int e = id & 7, lane = (id >> 3) & 63, tile = id >> 9;  // tile = colTile*4 + kTile
    int colTile = tile >> 2, kTile = tile & 3;
    int col = colTile * 16 + (lane & 15);
    int k = kTile * 32 + (lane >> 4) * 8 + e;
    w0t[id] = f2bf(scW0[k * FCH + col]);
  } else {
    int id = (blk - 790) * 256 + t;   // 262144
    int e = id & 7, lane = (id >> 3) & 63, tile = id >> 9;  // tile = colTile*16 + kTile
    int colTile = tile >> 4, kTile = tile & 15;
    int col = colTile * 16 + (lane & 15);
    int k = kTile * 32 + (lane >> 4) * 8 + e;
    w1t[id] = f2bf(scW1[k * FCH + col]);
  }
}

// ---------------- per-node geometry ----------------
__global__ void k_node(const float* frac, const float* noise, const int* batch, float* ws) {
  int n = blockIdx.x * blockDim.x + threadIdx.x;
  if (n >= Nn) return;
  int b = batch[n];
  float L[9], Li[9];
#pragma unroll
  for (int i = 0; i < 9; ++i) { L[i] = ws[WS_L + b * 9 + i]; Li[i] = ws[WS_LI + b * 9 + i]; }
  float f0 = frac[n * 3], f1 = frac[n * 3 + 1], f2 = frac[n * 3 + 2];
  float cg[3], p0[3], fp[3], pe[3], fg[3], fd[3];
#pragma unroll
  for (int j = 0; j < 3; ++j) cg[j] = f0 * L[j] + f1 * L[3 + j] + f2 * L[6 + j];
  float sig = ws[WS_SIG + b];
#pragma unroll
  for (int j = 0; j < 3; ++j) p0[j] = cg[j] + sig * noise[n * 3 + j];
#pragma unroll
  for (int j = 0; j < 3; ++j) {
    float v = p0[0] * Li[j] + p0[1] * Li[3 + j] + p0[2] * Li[6 + j];
    fp[j] = v - floorf(v);
  }
#pragma unroll
  for (int j = 0; j < 3; ++j) pe[j] = fp[0] * L[j] + fp[1] * L[3 + j] + fp[2] * L[6 + j];
#pragma unroll
  for (int j = 0; j < 3; ++j) fg[j] = cg[0] * Li[j] + cg[1] * Li[3 + j] + cg[2] * Li[6 + j];
#pragma unroll
  for (int j = 0; j < 3; ++j) { float d = fg[j] - fp[j]; fd[j] = d - rintf(d); }
#pragma unroll
  for (int j = 0; j < 3; ++j) {
    ws[WS_PERT + n * 3 + j] = pe[j];
    ws[WS_ALIGN + n * 3 + j] = pe[j] + fd[0] * L[j] + fd[1] * L[3 + j] + fd[2] * L[6 + j];
  }
}

// ---------------- the big fused MFMA edge kernel ----------------
// Tile: 64 edges x 512 cols. 8 waves of 64; wave wv owns cols [wv*64, wv*64+64)
// (4 col-tiles) x all 4 edge m-tiles -> acc[4][4]; each B fragment feeds 4 MFMAs,
// so W0+W1 stream from L2 exactly ONCE per 64 edges (half of round-7 traffic).
// LDS ~69.5 KB -> 2 blocks/CU (16 waves/CU). s_ef (16KB, swizzled [64][256B])
// ALIASES s_hh bytes 0..16383; rbfW2 (8KB) at +16384; cvec (512B) at +24576 —
// all dead before the GEMM1 epilogue overwrites s_hh (barrier-enforced).
// mfma_f32_16x16x32_bf16: A-frag lane l holds A[l&15][8*(l>>4)+e];
// B-frag lane l holds B[8*(l>>4)+e][l&15]; D: col=l&15, row=(l>>4)*4+r.
__global__ __launch_bounds__(512, 4) void k_edge(
    const int* ei, const int* toj, const int* batch, const int* atype,
    const unsigned short* w0t, const unsigned short* w1t,
    const float* scb1, const float* scW2, const float* scb2, float* ws) {
  __shared__ unsigned short s_hh[TE * FCH];   // 64 KB, XOR-swizzled rows (1024B)
  __shared__ float s_dvec[TE][3];
  __shared__ float s_dist[TE], s_gtd[TE];
  __shared__ int s_tj[TE], s_ti[TE];
  __shared__ float s_wsum[8][TE];             // 2 KB

  char* s_hh_b = (char*)s_hh;
  char* s_ef_b = s_hh_b;                          // alias: [64][256B] swizzled
  float* s_rbfw2 = (float*)(s_hh_b + 16384);      // [16][128] f32 (8 KB)
  float* s_cvec  = (float*)(s_hh_b + 24576);      // [128] f32 (512 B)

  const int t = threadIdx.x;
  const int e0 = blockIdx.x * TE;
  const int b0 = batch[ei[e0]];

  // ---- Phase A: stage rbfW2+cvec to LDS; per-edge geometry (t<64)
  {
    const float4* src = (const float4*)(ws + WS_RBFW2);  // 512 float4
    float4* dst = (float4*)s_rbfw2;
    dst[t] = src[t];
    if (t < 32) ((float4*)s_cvec)[t] = ((const float4*)(ws + WS_CVEC))[t];
  }
  if (t < TE) {
    int e = e0 + t;
    int jn = ei[e], iN = ei[Ee + e];
    int b = batch[jn];
    float tx = (float)toj[e * 3], ty = (float)toj[e * 3 + 1], tz = (float)toj[e * 3 + 2];
    const float* L = ws + WS_L + b * 9;
    float dv[3], gv[3];
#pragma unroll
    for (int j = 0; j < 3; ++j) {
      float off = tx * L[j] + ty * L[3 + j] + tz * L[6 + j];
      dv[j] = ws[WS_PERT + iN * 3 + j] - ws[WS_PERT + jn * 3 + j] - off;
      gv[j] = ws[WS_ALIGN + iN * 3 + j] - ws[WS_ALIGN + jn * 3 + j] - off;
    }
    float dist = sqrtf(dv[0] * dv[0] + dv[1] * dv[1] + dv[2] * dv[2]);
    float gtd = sqrtf(gv[0] * gv[0] + gv[1] * gv[1] + gv[2] * gv[2]);
#pragma unroll
    for (int j = 0; j < 3; ++j) s_dvec[t][j] = dv[j];
    s_dist[t] = dist;
    s_gtd[t] = gtd;
    s_tj[t] = atype[jn]; s_ti[t] = atype[iN];
  }
  __syncthreads();

  // ---- Phase B: ef = silu(hb[tj]+hb[ti]+rbf@rbfW2+cvec) -> bf16 s_ef (swizzled)
  {
    int e = t >> 3;              // 0..63
    int c0 = (t & 7) * 16;       // 16 cols per thread
    int tj = s_tj[e], ti = s_ti[e];
    float dist = s_dist[e];
    const float step = 7.0f / 15.0f;
    float rb[NRBF];
#pragma unroll
    for (int k = 0; k < NRBF; ++k) {
      float d = dist - (float)k * step;
      rb[k] = __expf(-10.f * d * d);
    }
    float4 z4[4];
#pragma unroll
    for (int q = 0; q < 4; ++q) {
      float4 a = *(const float4*)(ws + WS_HB + tj * HID + c0 + q * 4);
      float4 bq = *(const float4*)(ws + WS_HB + ti * HID + c0 + q * 4);
      float4 cv = ((const float4*)s_cvec)[c0 / 4 + q];
      z4[q].x = a.x + bq.x + cv.x; z4[q].y = a.y + bq.y + cv.y;
      z4[q].z = a.z + bq.z + cv.z; z4[q].w = a.w + bq.w + cv.w;
    }
#pragma unroll
    for (int k = 0; k < NRBF; ++k) {
      float rbk = rb[k];
#pragma unroll
      for (int q = 0; q < 4; ++q) {
        float4 wv4 = ((const float4*)s_rbfw2)[k * 32 + c0 / 4 + q];
        z4[q].x += rbk * wv4.x; z4[q].y += rbk * wv4.y;
        z4[q].z += rbk * wv4.z; z4[q].w += rbk * wv4.w;
      }
    }
    float sv[16];
#pragma unroll
    for (int q = 0; q < 4; ++q) {
      sv[q * 4 + 0] = z4[q].x / (1.f + __expf(-z4[q].x));
      sv[q * 4 + 1] = z4[q].y / (1.f + __expf(-z4[q].y));
      sv[q * 4 + 2] = z4[q].z / (1.f + __expf(-z4[q].z));
      sv[q * 4 + 3] = z4[q].w / (1.f + __expf(-z4[q].w));
    }
    unsigned int w[8];
#pragma unroll
    for (int p = 0; p < 8; ++p) w[p] = pk2bf(sv[2 * p], sv[2 * p + 1]);
    uint4 o0 = {w[0], w[1], w[2], w[3]};
    uint4 o1 = {w[4], w[5], w[6], w[7]};
    __syncthreads();   // all rbfw2/cvec LDS reads done before s_ef writes (alias safety)
    int base = e * 256 + c0 * 2;
    int sw = (e & 7) << 4;
    *(uint4*)(s_ef_b + ((base) ^ sw)) = o0;
    *(uint4*)(s_ef_b + ((base + 16) ^ sw)) = o1;
  }
  __syncthreads();

  const int lane = t & 63;
  const int wv = t >> 6;        // 0..7
  const int c0w = wv * 64;
  const int lr = lane & 15;     // col (D) / row (A) index
  const int lq = lane >> 4;     // k-quadrant

  // ---- Phase C: GEMM1  hh = relu(ef @ W0a + latp), bf16 -> s_hh (swizzled)
  {
    f32x4 acc[4][4];
#pragma unroll
    for (int m = 0; m < 4; ++m)
#pragma unroll
      for (int n = 0; n < 4; ++n) acc[m][n] = (f32x4){0.f, 0.f, 0.f, 0.f};
    const unsigned short* w0base = w0t + (size_t)(wv * 4) * 4 * 512 + lane * 8;
    // preload ALL W0 fragments for this wave (16 frags)
    bf16x8 bw[4][4];
#pragma unroll
    for (int kt = 0; kt < 4; ++kt)
#pragma unroll
      for (int n = 0; n < 4; ++n)
        bw[kt][n] = *(const bf16x8*)(w0base + (size_t)(n * 4 + kt) * 512);
#pragma unroll
    for (int kt = 0; kt < 4; ++kt) {
      bf16x8 a[4];
#pragma unroll
      for (int m = 0; m < 4; ++m) {
        int row = m * 16 + lr;
        int off = (row * 256 + (kt * 32 + lq * 8) * 2) ^ ((row & 7) << 4);
        a[m] = *(const bf16x8*)(s_ef_b + off);
      }
      __builtin_amdgcn_s_setprio(1);
#pragma unroll
      for (int n = 0; n < 4; ++n)
#pragma unroll
        for (int m = 0; m < 4; ++m)
          acc[m][n] = __builtin_amdgcn_mfma_f32_16x16x32_bf16(a[m], bw[kt][n], acc[m][n], 0, 0, 0);
      __builtin_amdgcn_s_setprio(0);
    }
    __syncthreads();   // ALL s_ef reads complete before epilogue overwrites the alias
#pragma unroll
    for (int m = 0; m < 4; ++m)
#pragma unroll
      for (int n = 0; n < 4; ++n) {
        int col = c0w + n * 16 + lr;
        float lp = ws[WS_LATP + b0 * FCH + col];
        f32x4 v = acc[m][n];
#pragma unroll
        for (int rp = 0; rp < 2; ++rp) {
          float h0 = fmaxf(v[2 * rp] + lp, 0.f);
          float h1 = fmaxf(v[2 * rp + 1] + lp, 0.f);
          unsigned int ui = pk2bf(h0, h1);
          int row0 = m * 16 + lq * 4 + 2 * rp;
          int row1 = row0 + 1;
          int off0 = (row0 * 1024 + col * 2) ^ ((row0 & 7) << 4);
          int off1 = (row1 * 1024 + col * 2) ^ ((row1 & 7) << 4);
          *(unsigned short*)(s_hh_b + off0) = (unsigned short)(ui & 0xffffu);
          *(unsigned short*)(s_hh_b + off1) = (unsigned short)(ui >> 16);
        }
      }
  }
  __syncthreads();

  // ---- Phase D: GEMM2 + fused score reduction (B reused 4x per load)
  {
    f32x4 acc[4][4];
#pragma unroll
    for (int m = 0; m < 4; ++m)
#pragma unroll
      for (int n = 0; n < 4; ++n) acc[m][n] = (f32x4){0.f, 0.f, 0.f, 0.f};
    const unsigned short* w1base = w1t + (size_t)(wv * 4) * 16 * 512 + lane * 8;
#pragma unroll 4
    for (int kt = 0; kt < 16; ++kt) {
      bf16x8 bfr[4];
#pragma unroll
      for (int n = 0; n < 4; ++n)
        bfr[n] = *(const bf16x8*)(w1base + (size_t)(n * 16 + kt) * 512);
      bf16x8 a[4];
#pragma unroll
      for (int m = 0; m < 4; ++m) {
        int row = m * 16 + lr;
        int off = (row * 1024 + (kt * 32 + lq * 8) * 2) ^ ((row & 7) << 4);
        a[m] = *(const bf16x8*)(s_hh_b + off);
      }
      __builtin_amdgcn_s_setprio(1);
#pragma unroll
      for (int n = 0; n < 4; ++n)
#pragma unroll
        for (int m = 0; m < 4; ++m)
          acc[m][n] = __builtin_amdgcn_mfma_f32_16x16x32_bf16(a[m], bfr[n], acc[m][n], 0, 0, 0);
      __builtin_amdgcn_s_setprio(0);
    }
    // hh1 = relu(acc + b1); p += hh1 * W2   (per lane: 4 cols x 16 rows)
    float p[4][4];
#pragma unroll
    for (int m = 0; m < 4; ++m)
#pragma unroll
      for (int r = 0; r < 4; ++r) p[m][r] = 0.f;
#pragma unroll
    for (int n = 0; n < 4; ++n) {
      int col = c0w + n * 16 + lr;
      float b1v = scb1[col];
      float w2v = scW2[col];
#pragma unroll
      for (int m = 0; m < 4; ++m) {
        f32x4 v = acc[m][n];
#pragma unroll
        for (int r = 0; r < 4; ++r) p[m][r] += fmaxf(v[r] + b1v, 0.f) * w2v;
      }
    }
    // reduce over the 16 lanes sharing a row (lane bits 0..3)
#pragma unroll
    for (int m = 0; m < 4; ++m)
#pragma unroll
      for (int r = 0; r < 4; ++r) {
        float x = p[m][r];
        x += __shfl_xor(x, 1);
        x += __shfl_xor(x, 2);
        x += __shfl_xor(x, 4);
        x += __shfl_xor(x, 8);
        p[m][r] = x;
      }
    if (lr == 0) {
#pragma unroll
      for (int m = 0; m < 4; ++m)
#pragma unroll
        for (int r = 0; r < 4; ++r) s_wsum[wv][m * 16 + lq * 4 + r] = p[m][r];
    }
  }
  __syncthreads();

  // ---- Phase E: segment-mean scatter (threads 0..63)
  if (t < TE) {
    int e = e0 + t;
    float score = scb2[0];
#pragma unroll
    for (int w = 0; w < 8; ++w) score += s_wsum[w][t];
    int jn = ei[e], iN = ei[Ee + e];
    int s = e;
    while (s > 0 && ei[s - 1] == jn && ei[Ee + s - 1] == iN) --s;
    int en = e;
    while (en + 1 < Ee && ei[en + 1] == jn && ei[Ee + en + 1] == iN) ++en;
    float invc = 1.f / (float)(en - s + 1);
    float dist = s_dist[t];
    float denom = dist + 1e-8f;
    float gts = s_gtd[t] - dist;
#pragma unroll
    for (int j = 0; j < 3; ++j) {
      float dir = s_dvec[t][j] / denom;
      atomicAdd(&ws[WS_SN + iN * 3 + j], score * dir * invc);
      atomicAdd(&ws[WS_GN + iN * 3 + j], gts * dir * invc);
    }
  }
}

// ---------------- per-node: loss terms, preds, center sums ----------------
__global__ void k_node2(const int* batch, float* ws) {
  int n = blockIdx.x * blockDim.x + threadIdx.x;
  if (n >= Nn) return;
  int b = batch[n];
  float sig = ws[WS_SIG + b];
#pragma unroll
  for (int j = 0; j < 3; ++j) {
    float s = ws[WS_SN + n * 3 + j], g = ws[WS_GN + n * 3 + j];
    float d = s - g / sig;
    atomicAdd(&ws[WS_BSUM + b * 3 + j], d * d);
    float pr = ws[WS_PERT + n * 3 + j] + s / sig;
    ws[WS_PREDS + n * 3 + j] = pr;
    atomicAdd(&ws[WS_CENTER + b * 3 + j], pr);
  }
}

// ---------------- per-node: global min/max of dc ----------------
__global__ void k_minmax(const int* batch, const int* num_atoms, float* ws) {
  int n = blockIdx.x * blockDim.x + threadIdx.x;
  int lane = threadIdx.x & 63, wid = threadIdx.x >> 6;
  float mx[3], mn[3];
  if (n < Nn) {
    int b = batch[n];
    float na = (float)num_atoms[b];
#pragma unroll
    for (int j = 0; j < 3; ++j) {
      float v = ws[WS_PREDS + n * 3 + j] - ws[WS_CENTER + b * 3 + j] / na;
      mx[j] = v; mn[j] = v;
    }
  } else {
#pragma unroll
    for (int j = 0; j < 3; ++j) { mx[j] = -3.0e38f; mn[j] = 3.0e38f; }
  }
#pragma unroll
  for (int off = 32; off >= 1; off >>= 1) {
#pragma unroll
    for (int j = 0; j < 3; ++j) {
      mx[j] = fmaxf(mx[j], __shfl_xor(mx[j], off));
      mn[j] = fminf(mn[j], __shfl_xor(mn[j], off));
    }
  }
  __shared__ float smx[4][3], smn[4][3];
  if (lane == 0) {
#pragma unroll
    for (int j = 0; j < 3; ++j) { smx[wid][j] = mx[j]; smn[wid][j] = mn[j]; }
  }
  __syncthreads();
  if (threadIdx.x == 0) {
#pragma unroll
    for (int j = 0; j < 3; ++j) {
      float M = fmaxf(fmaxf(smx[0][j], smx[1][j]), fmaxf(smx[2][j], smx[3][j]));
      float m = fminf(fminf(smn[0][j], smn[1][j]), fminf(smn[2][j], smn[3][j]));
      atomicMaxFloat(&ws[WS_MINMAX + j], M);
      atomicMinFloat(&ws[WS_MINMAX + 3 + j], m);
    }
  }
}

// ---------------- finalize (parallel over batches) ----------------
__global__ void k_final(const int* num_atoms, const float* ws, float* out) {
  int t = threadIdx.x;  // 128 threads
  float loss = 0.f;
  if (t < Bb) {
    float na = (float)num_atoms[t];
    loss = (ws[WS_BSUM + t * 3] + ws[WS_BSUM + t * 3 + 1] + ws[WS_BSUM + t * 3 + 2]) / na;
  }
#pragma unroll
  for (int off = 32; off >= 1; off >>= 1) loss += __shfl_xor(loss, off);
  __shared__ float s2[2];
  if ((t & 63) == 0) s2[t >> 6] = loss;
  __syncthreads();
  if (t == 0) {
    float L = (s2[0] + s2[1]) / (3.0f * (float)Bb);
    float pbs = fabsf(ws[WS_MINMAX + 0] + ws[WS_MINMAX + 3]) +
                fabsf(ws[WS_MINMAX + 1] + ws[WS_MINMAX + 4]) +
                fabsf(ws[WS_MINMAX + 2] + ws[WS_MINMAX + 5]);
    out[0] = L;
    out[1] = pbs;
  }
}

extern "C" void kernel_launch(void* const* d_in, const int* in_sizes, int n_in,
                              void* d_out, int out_size, void* d_ws, size_t ws_size,
                              hipStream_t stream) {
  const float* latents = (const float*)d_in[0];
  const float* gtf     = (const float*)d_in[1];
  const float* lengths = (const float*)d_in[2];
  const float* angles  = (const float*)d_in[3];
  const float* noise   = (const float*)d_in[4];
  const float* sigmas  = (const float*)d_in[5];
  const float* aemb    = (const float*)d_in[6];
  const float* rbfW    = (const float*)d_in[7];
  const float* rbfb    = (const float*)d_in[8];
  const float* bbW     = (const float*)d_in[9];
  const float* bbb     = (const float*)d_in[10];
  const float* scW0    = (const float*)d_in[11];
  const float* scb0    = (const float*)d_in[12];
  const float* scW1    = (const float*)d_in[13];
  const float* scb1    = (const float*)d_in[14];
  const float* scW2    = (const float*)d_in[15];
  const float* scb2    = (const float*)d_in[16];
  const int* num_atoms = (const int*)d_in[17];
  const int* atype     = (const int*)d_in[18];
  const int* batch     = (const int*)d_in[19];
  const int* ei        = (const int*)d_in[20];
  const int* toj       = (const int*)d_in[21];
  const int* tsteps    = (const int*)d_in[22];
  float* ws = (float*)d_ws;
  float* out = (float*)d_out;
  unsigned short* w0t = (unsigned short*)(ws + WS_W0T_F);
  unsigned short* w1t = (unsigned short*)(ws + WS_W1T_F);

  hipLaunchKernelGGL(k_pre, dim3(1814), dim3(256), 0, stream,
                     lengths, angles, sigmas, tsteps, aemb, bbW, rbfW, rbfb, bbb,
                     latents, scW0, scb0, scW1, w0t, w1t, ws);
  hipLaunchKernelGGL(k_node, dim3(50), dim3(256), 0, stream, gtf, noise, batch, ws);
  hipLaunchKernelGGL(k_edge, dim3(Ee / TE), dim3(512), 0, stream,
                     ei, toj, batch, atype, w0t, w1t, scb1, scW2, scb2, ws);
  hipLaunchKernelGGL(k_node2, dim3(50), dim3(256), 0, stream, batch, ws);
  hipLaunchKernelGGL(k_minmax, dim3(50), dim3(256), 0, stream, batch, num_atoms, ws);
  hipLaunchKernelGGL(k_final, dim3(1), dim3(128), 0, stream, num_atoms, ws, out);
}

// Round 9
// 360.338 us; speedup vs baseline: 1.0831x; 1.0831x over previous
//
#include <hip/hip_runtime.h>
#include <hip/hip_bf16.h>

// ---------------- problem constants ----------------
namespace {
constexpr int Bb = 128, Nn = 12800, Ee = 262144;
constexpr int LAT = 256, HID = 128, FCH = 512, NRBF = 16;
constexpr int TE = 64; // edges per block in edge kernel (divides 2048 = edges/graph)

// workspace offsets (floats)
constexpr int WS_L      = 0;        // B*9
constexpr int WS_LI     = 1152;     // B*9
constexpr int WS_SIG    = 2304;     // B
constexpr int WS_RBFW2  = 2432;     // 16*128
constexpr int WS_CVEC   = 4480;     // 128
constexpr int WS_HB     = 4608;     // 100*128
constexpr int WS_LATP   = 17408;    // B*512
constexpr int WS_PERT   = 82944;    // N*3
constexpr int WS_ALIGN  = 121344;   // N*3
constexpr int WS_SN     = 159744;   // N*3 (atomic)
constexpr int WS_GN     = 198144;   // N*3 (atomic)
constexpr int WS_PREDS  = 236544;   // N*3
constexpr int WS_BSUM   = 274944;   // B*3 (atomic)
constexpr int WS_CENTER = 275328;   // B*3 (atomic)
constexpr int WS_MINMAX = 275712;   // 6   (max x3, min x3)
// bf16 fragment-tiled weights (stored as ushort), float-index base:
constexpr int WS_W0T_F  = 276000;   // ushort[512*128]  (= 32768 floats)
constexpr int WS_W1T_F  = 308768;   // ushort[512*512]  (= 131072 floats)
}

typedef short bf16x8 __attribute__((ext_vector_type(8)));
typedef float f32x4 __attribute__((ext_vector_type(4)));

static __device__ __forceinline__ unsigned short f2bf(float f) {
  unsigned int u = __float_as_uint(f);
  unsigned int r = (u + 0x7fffu + ((u >> 16) & 1u)) >> 16;
  return (unsigned short)r;
}
// packed pair: returns uint with bf16(a) in low16, bf16(b) in high16
static __device__ __forceinline__ unsigned int pk2bf(float a, float b) {
  __hip_bfloat162 h2 = __float22bfloat162_rn(make_float2(a, b));
  return *reinterpret_cast<unsigned int*>(&h2);
}

static __device__ __forceinline__ void atomicMaxFloat(float* addr, float val) {
  int* ai = reinterpret_cast<int*>(addr);
  int old = *ai;
  while (__int_as_float(old) < val) {
    int assumed = old;
    old = atomicCAS(ai, assumed, __float_as_int(val));
    if (old == assumed) break;
  }
}
static __device__ __forceinline__ void atomicMinFloat(float* addr, float val) {
  int* ai = reinterpret_cast<int*>(addr);
  int old = *ai;
  while (__int_as_float(old) > val) {
    int assumed = old;
    old = atomicCAS(ai, assumed, __float_as_int(val));
    if (old == assumed) break;
  }
}

// ---------------- fused prologue: all mutually-independent prep work ----------------
__global__ __launch_bounds__(256) void k_pre(
    const float* lengths, const float* angles, const float* sigmas, const int* tsteps,
    const float* aemb, const float* bbW, const float* rbfW, const float* rbfb,
    const float* bbb, const float* latents, const float* scW0, const float* scb0,
    const float* scW1, unsigned short* w0t, unsigned short* w1t, float* ws) {
  const int blk = blockIdx.x, t = threadIdx.x;
  if (blk < 304) {
    int gid = blk * 256 + t;
    if (gid < 2 * Nn * 3) ws[WS_SN + gid] = 0.f;
    else if (gid < 2 * Nn * 3 + 2 * Bb * 3) ws[WS_BSUM + (gid - 2 * Nn * 3)] = 0.f;
    else if (gid < 2 * Nn * 3 + 2 * Bb * 3 + 3) ws[WS_MINMAX + (gid - 2 * Nn * 3 - 2 * Bb * 3)] = -3.0e38f;
    else if (gid < 2 * Nn * 3 + 2 * Bb * 3 + 6) ws[WS_MINMAX + (gid - 2 * Nn * 3 - 2 * Bb * 3)] = 3.0e38f;
  } else if (blk == 304) {
    int b = t;
    if (b >= Bb) return;
    float a = lengths[b * 3 + 0], bl = lengths[b * 3 + 1], c = lengths[b * 3 + 2];
    const float d2r = 0.017453292519943295f;
    float al = angles[b * 3 + 0] * d2r, be = angles[b * 3 + 1] * d2r, ga = angles[b * 3 + 2] * d2r;
    float ca = cosf(al), cb = cosf(be), cg = cosf(ga), sa = sinf(al), sb = sinf(be);
    float val = (ca * cb - cg) / (sa * sb);
    val = fminf(1.f, fmaxf(-1.f, val));
    float gs = acosf(val);
    float L[3][3];
    L[0][0] = a * sb;              L[0][1] = 0.f;                L[0][2] = a * cb;
    L[1][0] = -bl * sa * cosf(gs); L[1][1] = bl * sa * sinf(gs); L[1][2] = bl * ca;
    L[2][0] = 0.f;                 L[2][1] = 0.f;                L[2][2] = c;
    float det = L[0][0] * (L[1][1] * L[2][2] - L[1][2] * L[2][1])
              - L[0][1] * (L[1][0] * L[2][2] - L[1][2] * L[2][0])
              + L[0][2] * (L[1][0] * L[2][1] - L[1][1] * L[2][0]);
    float id = 1.f / det;
    float inv[3][3];
    inv[0][0] =  (L[1][1]*L[2][2] - L[1][2]*L[2][1]) * id;
    inv[0][1] = -(L[0][1]*L[2][2] - L[0][2]*L[2][1]) * id;
    inv[0][2] =  (L[0][1]*L[1][2] - L[0][2]*L[1][1]) * id;
    inv[1][0] = -(L[1][0]*L[2][2] - L[1][2]*L[2][0]) * id;
    inv[1][1] =  (L[0][0]*L[2][2] - L[0][2]*L[2][0]) * id;
    inv[1][2] = -(L[0][0]*L[1][2] - L[0][2]*L[1][0]) * id;
    inv[2][0] =  (L[1][0]*L[2][1] - L[1][1]*L[2][0]) * id;
    inv[2][1] = -(L[0][0]*L[2][1] - L[0][1]*L[2][0]) * id;
    inv[2][2] =  (L[0][0]*L[1][1] - L[0][1]*L[1][0]) * id;
    for (int i = 0; i < 3; ++i)
      for (int j = 0; j < 3; ++j) {
        ws[WS_L + b * 9 + i * 3 + j] = L[i][j];
        ws[WS_LI + b * 9 + i * 3 + j] = inv[i][j];
      }
    ws[WS_SIG + b] = sigmas[tsteps[b]];
  } else if (blk < 405) {
    int tile = blk - 305;
    if (t < HID) {
      float acc = 0.f;
      for (int k = 0; k < HID; ++k) acc += aemb[tile * HID + k] * bbW[k * HID + t];
      ws[WS_HB + tile * HID + t] = acc;
    }
  } else if (blk == 405) {
    if (t < HID) {
      float accs[NRBF];
#pragma unroll
      for (int k = 0; k < NRBF; ++k) accs[k] = 0.f;
      float accb = 0.f;
      for (int m = 0; m < HID; ++m) {
        float w = bbW[m * HID + t];
#pragma unroll
        for (int k = 0; k < NRBF; ++k) accs[k] += rbfW[k * HID + m] * w;
        accb += rbfb[m] * w;
      }
#pragma unroll
      for (int k = 0; k < NRBF; ++k) ws[WS_RBFW2 + k * HID + t] = accs[k];
      ws[WS_CVEC + t] = accb + bbb[t];
    }
  } else if (blk < 534) {
    int b = blk - 406;
    __shared__ float lat[LAT];
    lat[t] = latents[b * LAT + t];
    __syncthreads();
    int c0 = 2 * t;
    float a0 = 0.f, a1 = 0.f;
    for (int m = 0; m < LAT; ++m) {
      float2 w = *reinterpret_cast<const float2*>(scW0 + (HID + m) * FCH + c0);
      float lm = lat[m];
      a0 += lm * w.x;
      a1 += lm * w.y;
    }
    ws[WS_LATP + b * FCH + c0] = a0 + scb0[c0];
    ws[WS_LATP + b * FCH + c0 + 1] = a1 + scb0[c0 + 1];
  } else if (blk < 790) {
    // cvtW0: coalesced read scW0[tid] (tid = k*512+col, k<128), scattered 2B write
    int tid = (blk - 534) * 256 + t;   // 65536
    int col = tid & 511, k = tid >> 9;
    int id = (((col >> 4) * 4 + (k >> 5)) * 64 + ((k & 31) >> 3) * 16 + (col & 15)) * 8 + (k & 7);
    w0t[id] = f2bf(scW0[tid]);
  } else {
    // cvtW1: coalesced read scW1[tid] (tid = k*512+col, k<512), scattered 2B write
    int tid = (blk - 790) * 256 + t;   // 262144
    int col = tid & 511, k = tid >> 9;
    int id = (((col >> 4) * 16 + (k >> 5)) * 64 + ((k & 31) >> 3) * 16 + (col & 15)) * 8 + (k & 7);
    w1t[id] = f2bf(scW1[tid]);
  }
}

// ---------------- per-node geometry ----------------
__global__ void k_node(const float* frac, const float* noise, const int* batch, float* ws) {
  int n = blockIdx.x * blockDim.x + threadIdx.x;
  if (n >= Nn) return;
  int b = batch[n];
  float L[9], Li[9];
#pragma unroll
  for (int i = 0; i < 9; ++i) { L[i] = ws[WS_L + b * 9 + i]; Li[i] = ws[WS_LI + b * 9 + i]; }
  float f0 = frac[n * 3], f1 = frac[n * 3 + 1], f2 = frac[n * 3 + 2];
  float cg[3], p0[3], fp[3], pe[3], fg[3], fd[3];
#pragma unroll
  for (int j = 0; j < 3; ++j) cg[j] = f0 * L[j] + f1 * L[3 + j] + f2 * L[6 + j];
  float sig = ws[WS_SIG + b];
#pragma unroll
  for (int j = 0; j < 3; ++j) p0[j] = cg[j] + sig * noise[n * 3 + j];
#pragma unroll
  for (int j = 0; j < 3; ++j) {
    float v = p0[0] * Li[j] + p0[1] * Li[3 + j] + p0[2] * Li[6 + j];
    fp[j] = v - floorf(v);
  }
#pragma unroll
  for (int j = 0; j < 3; ++j) pe[j] = fp[0] * L[j] + fp[1] * L[3 + j] + fp[2] * L[6 + j];
#pragma unroll
  for (int j = 0; j < 3; ++j) fg[j] = cg[0] * Li[j] + cg[1] * Li[3 + j] + cg[2] * Li[6 + j];
#pragma unroll
  for (int j = 0; j < 3; ++j) { float d = fg[j] - fp[j]; fd[j] = d - rintf(d); }
#pragma unroll
  for (int j = 0; j < 3; ++j) {
    ws[WS_PERT + n * 3 + j] = pe[j];
    ws[WS_ALIGN + n * 3 + j] = pe[j] + fd[0] * L[j] + fd[1] * L[3 + j] + fd[2] * L[6 + j];
  }
}

// ---------------- the big fused MFMA edge kernel ----------------
// Tile: 64 edges x 512 cols. 8 waves of 64; wave wv owns cols [wv*64, wv*64+64)
// (4 col-tiles) x all 4 edge m-tiles -> acc[4][4]; each B fragment feeds 4 MFMAs,
// so W0+W1 stream from L2 exactly ONCE per 64 edges.
// W0 fragments are loaded per-kt (4 live regs), NOT preloaded — r8's 16-frag
// preload pushed peak pressure past the 128-reg budget and spilled 64B/thread
// (WRITE_SIZE 135 MB of scratch).
// LDS ~68.7 KB -> 2 blocks/CU (16 waves/CU). Alias plan inside s_hh (64KB):
//   s_ef   bytes [0, 16384)       swizzled [64][256B]   (Phase B write, C read)
//   rbfw2  bytes [16384, 24576)   f32[16][128]          (Phase A write, B read)
//   cvec   bytes [24576, 25088)   f32[128]
//   rbfE   bytes [25088, 29184)   f32[64][16] per-edge rbf (A write, B read)
// All dead before the GEMM1 epilogue overwrites s_hh (barrier-enforced).
// mfma_f32_16x16x32_bf16: A-frag lane l holds A[l&15][8*(l>>4)+e];
// B-frag lane l holds B[8*(l>>4)+e][l&15]; D: col=l&15, row=(l>>4)*4+r.
__global__ __launch_bounds__(512, 4) void k_edge(
    const int* ei, const int* toj, const int* batch, const int* atype,
    const unsigned short* w0t, const unsigned short* w1t,
    const float* scb1, const float* scW2, const float* scb2, float* ws) {
  __shared__ unsigned short s_hh[TE * FCH];   // 64 KB, XOR-swizzled rows (1024B)
  __shared__ float s_dvec[TE][3];
  __shared__ float s_dist[TE], s_gtd[TE];
  __shared__ int s_tj[TE], s_ti[TE];
  __shared__ float s_wsum[8][TE];             // 2 KB

  char* s_hh_b = (char*)s_hh;
  char* s_ef_b = s_hh_b;                          // alias: [64][256B] swizzled
  float* s_rbfw2 = (float*)(s_hh_b + 16384);      // [16][128] f32 (8 KB)
  float* s_cvec  = (float*)(s_hh_b + 24576);      // [128] f32 (512 B)
  float* s_rbfE  = (float*)(s_hh_b + 25088);      // [64][16] f32 (4 KB)

  const int t = threadIdx.x;
  const int e0 = blockIdx.x * TE;
  const int b0 = batch[ei[e0]];

  // ---- Phase A: stage rbfW2+cvec to LDS; per-edge geometry + rbf (t<64)
  {
    const float4* src = (const float4*)(ws + WS_RBFW2);  // 512 float4
    float4* dst = (float4*)s_rbfw2;
    dst[t] = src[t];
    if (t < 32) ((float4*)s_cvec)[t] = ((const float4*)(ws + WS_CVEC))[t];
  }
  if (t < TE) {
    int e = e0 + t;
    int jn = ei[e], iN = ei[Ee + e];
    int b = batch[jn];
    float tx = (float)toj[e * 3], ty = (float)toj[e * 3 + 1], tz = (float)toj[e * 3 + 2];
    const float* L = ws + WS_L + b * 9;
    float dv[3], gv[3];
#pragma unroll
    for (int j = 0; j < 3; ++j) {
      float off = tx * L[j] + ty * L[3 + j] + tz * L[6 + j];
      dv[j] = ws[WS_PERT + iN * 3 + j] - ws[WS_PERT + jn * 3 + j] - off;
      gv[j] = ws[WS_ALIGN + iN * 3 + j] - ws[WS_ALIGN + jn * 3 + j] - off;
    }
    float dist = sqrtf(dv[0] * dv[0] + dv[1] * dv[1] + dv[2] * dv[2]);
    float gtd = sqrtf(gv[0] * gv[0] + gv[1] * gv[1] + gv[2] * gv[2]);
#pragma unroll
    for (int j = 0; j < 3; ++j) s_dvec[t][j] = dv[j];
    s_dist[t] = dist;
    s_gtd[t] = gtd;
    s_tj[t] = atype[jn]; s_ti[t] = atype[iN];
    const float step = 7.0f / 15.0f;
#pragma unroll
    for (int k = 0; k < NRBF; ++k) {
      float d = dist - (float)k * step;
      s_rbfE[t * NRBF + k] = __expf(-10.f * d * d);
    }
  }
  __syncthreads();

  // ---- Phase B: ef = silu(hb[tj]+hb[ti]+rbf@rbfW2+cvec) -> bf16 s_ef (swizzled)
  {
    int e = t >> 3;              // 0..63
    int c0 = (t & 7) * 16;       // 16 cols per thread
    int tj = s_tj[e], ti = s_ti[e];
    float4 rb4[4];
#pragma unroll
    for (int q = 0; q < 4; ++q) rb4[q] = ((const float4*)(s_rbfE + e * NRBF))[q];
    float rb[NRBF] = {rb4[0].x, rb4[0].y, rb4[0].z, rb4[0].w,
                      rb4[1].x, rb4[1].y, rb4[1].z, rb4[1].w,
                      rb4[2].x, rb4[2].y, rb4[2].z, rb4[2].w,
                      rb4[3].x, rb4[3].y, rb4[3].z, rb4[3].w};
    float4 z4[4];
#pragma unroll
    for (int q = 0; q < 4; ++q) {
      float4 a = *(const float4*)(ws + WS_HB + tj * HID + c0 + q * 4);
      float4 bq = *(const float4*)(ws + WS_HB + ti * HID + c0 + q * 4);
      float4 cv = ((const float4*)s_cvec)[c0 / 4 + q];
      z4[q].x = a.x + bq.x + cv.x; z4[q].y = a.y + bq.y + cv.y;
      z4[q].z = a.z + bq.z + cv.z; z4[q].w = a.w + bq.w + cv.w;
    }
#pragma unroll
    for (int k = 0; k < NRBF; ++k) {
      float rbk = rb[k];
#pragma unroll
      for (int q = 0; q < 4; ++q) {
        float4 wv4 = ((const float4*)s_rbfw2)[k * 32 + c0 / 4 + q];
        z4[q].x += rbk * wv4.x; z4[q].y += rbk * wv4.y;
        z4[q].z += rbk * wv4.z; z4[q].w += rbk * wv4.w;
      }
    }
    float sv[16];
#pragma unroll
    for (int q = 0; q < 4; ++q) {
      sv[q * 4 + 0] = z4[q].x / (1.f + __expf(-z4[q].x));
      sv[q * 4 + 1] = z4[q].y / (1.f + __expf(-z4[q].y));
      sv[q * 4 + 2] = z4[q].z / (1.f + __expf(-z4[q].z));
      sv[q * 4 + 3] = z4[q].w / (1.f + __expf(-z4[q].w));
    }
    unsigned int w[8];
#pragma unroll
    for (int p = 0; p < 8; ++p) w[p] = pk2bf(sv[2 * p], sv[2 * p + 1]);
    uint4 o0 = {w[0], w[1], w[2], w[3]};
    uint4 o1 = {w[4], w[5], w[6], w[7]};
    // s_ef writes [0,16K) are disjoint from rbfw2/cvec/rbfE [16K,29K) — no barrier needed
    int base = e * 256 + c0 * 2;
    int sw = (e & 7) << 4;
    *(uint4*)(s_ef_b + ((base) ^ sw)) = o0;
    *(uint4*)(s_ef_b + ((base + 16) ^ sw)) = o1;
  }
  __syncthreads();

  const int lane = t & 63;
  const int wv = t >> 6;        // 0..7
  const int c0w = wv * 64;
  const int lr = lane & 15;     // col (D) / row (A) index
  const int lq = lane >> 4;     // k-quadrant

  // ---- Phase C: GEMM1  hh = relu(ef @ W0a + latp), bf16 -> s_hh (swizzled)
  {
    f32x4 acc[4][4];
#pragma unroll
    for (int m = 0; m < 4; ++m)
#pragma unroll
      for (int n = 0; n < 4; ++n) acc[m][n] = (f32x4){0.f, 0.f, 0.f, 0.f};
    const unsigned short* w0base = w0t + (size_t)(wv * 4) * 4 * 512 + lane * 8;
#pragma unroll
    for (int kt = 0; kt < 4; ++kt) {
      bf16x8 bw[4];
#pragma unroll
      for (int n = 0; n < 4; ++n)
        bw[n] = *(const bf16x8*)(w0base + (size_t)(n * 4 + kt) * 512);
      bf16x8 a[4];
#pragma unroll
      for (int m = 0; m < 4; ++m) {
        int row = m * 16 + lr;
        int off = (row * 256 + (kt * 32 + lq * 8) * 2) ^ ((row & 7) << 4);
        a[m] = *(const bf16x8*)(s_ef_b + off);
      }
      __builtin_amdgcn_s_setprio(1);
#pragma unroll
      for (int n = 0; n < 4; ++n)
#pragma unroll
        for (int m = 0; m < 4; ++m)
          acc[m][n] = __builtin_amdgcn_mfma_f32_16x16x32_bf16(a[m], bw[n], acc[m][n], 0, 0, 0);
      __builtin_amdgcn_s_setprio(0);
    }
    __syncthreads();   // ALL s_ef reads complete before epilogue overwrites the alias
#pragma unroll
    for (int m = 0; m < 4; ++m)
#pragma unroll
      for (int n = 0; n < 4; ++n) {
        int col = c0w + n * 16 + lr;
        float lp = ws[WS_LATP + b0 * FCH + col];
        f32x4 v = acc[m][n];
#pragma unroll
        for (int rp = 0; rp < 2; ++rp) {
          float h0 = fmaxf(v[2 * rp] + lp, 0.f);
          float h1 = fmaxf(v[2 * rp + 1] + lp, 0.f);
          unsigned int ui = pk2bf(h0, h1);
          int row0 = m * 16 + lq * 4 + 2 * rp;
          int row1 = row0 + 1;
          int off0 = (row0 * 1024 + col * 2) ^ ((row0 & 7) << 4);
          int off1 = (row1 * 1024 + col * 2) ^ ((row1 & 7) << 4);
          *(unsigned short*)(s_hh_b + off0) = (unsigned short)(ui & 0xffffu);
          *(unsigned short*)(s_hh_b + off1) = (unsigned short)(ui >> 16);
        }
      }
  }
  __syncthreads();

  // ---- Phase D: GEMM2 + fused score reduction (B reused 4x per load)
  {
    f32x4 acc[4][4];
#pragma unroll
    for (int m = 0; m < 4; ++m)
#pragma unroll
      for (int n = 0; n < 4; ++n) acc[m][n] = (f32x4){0.f, 0.f, 0.f, 0.f};
    const unsigned short* w1base = w1t + (size_t)(wv * 4) * 16 * 512 + lane * 8;
#pragma unroll 4
    for (int kt = 0; kt < 16; ++kt) {
      bf16x8 bfr[4];
#pragma unroll
      for (int n = 0; n < 4; ++n)
        bfr[n] = *(const bf16x8*)(w1base + (size_t)(n * 16 + kt) * 512);
      bf16x8 a[4];
#pragma unroll
      for (int m = 0; m < 4; ++m) {
        int row = m * 16 + lr;
        int off = (row * 1024 + (kt * 32 + lq * 8) * 2) ^ ((row & 7) << 4);
        a[m] = *(const bf16x8*)(s_hh_b + off);
      }
      __builtin_amdgcn_s_setprio(1);
#pragma unroll
      for (int n = 0; n < 4; ++n)
#pragma unroll
        for (int m = 0; m < 4; ++m)
          acc[m][n] = __builtin_amdgcn_mfma_f32_16x16x32_bf16(a[m], bfr[n], acc[m][n], 0, 0, 0);
      __builtin_amdgcn_s_setprio(0);
    }
    // hh1 = relu(acc + b1); p += hh1 * W2   (per lane: 4 cols x 16 rows)
    float p[4][4];
#pragma unroll
    for (int m = 0; m < 4; ++m)
#pragma unroll
      for (int r = 0; r < 4; ++r) p[m][r] = 0.f;
#pragma unroll
    for (int n = 0; n < 4; ++n) {
      int col = c0w + n * 16 + lr;
      float b1v = scb1[col];
      float w2v = scW2[col];
#pragma unroll
      for (int m = 0; m < 4; ++m) {
        f32x4 v = acc[m][n];
#pragma unroll
        for (int r = 0; r < 4; ++r) p[m][r] += fmaxf(v[r] + b1v, 0.f) * w2v;
      }
    }
    // reduce over the 16 lanes sharing a row (lane bits 0..3)
#pragma unroll
    for (int m = 0; m < 4; ++m)
#pragma unroll
      for (int r = 0; r < 4; ++r) {
        float x = p[m][r];
        x += __shfl_xor(x, 1);
        x += __shfl_xor(x, 2);
        x += __shfl_xor(x, 4);
        x += __shfl_xor(x, 8);
        p[m][r] = x;
      }
    if (lr == 0) {
#pragma unroll
      for (int m = 0; m < 4; ++m)
#pragma unroll
        for (int r = 0; r < 4; ++r) s_wsum[wv][m * 16 + lq * 4 + r] = p[m][r];
    }
  }
  __syncthreads();

  // ---- Phase E: segment-mean scatter (threads 0..63)
  if (t < TE) {
    int e = e0 + t;
    float score = scb2[0];
#pragma unroll
    for (int w = 0; w < 8; ++w) score += s_wsum[w][t];
    int jn = ei[e], iN = ei[Ee + e];
    int s = e;
    while (s > 0 && ei[s - 1] == jn && ei[Ee + s - 1] == iN) --s;
    int en = e;
    while (en + 1 < Ee && ei[en + 1] == jn && ei[Ee + en + 1] == iN) ++en;
    float invc = 1.f / (float)(en - s + 1);
    float dist = s_dist[t];
    float denom = dist + 1e-8f;
    float gts = s_gtd[t] - dist;
#pragma unroll
    for (int j = 0; j < 3; ++j) {
      float dir = s_dvec[t][j] / denom;
      atomicAdd(&ws[WS_SN + iN * 3 + j], score * dir * invc);
      atomicAdd(&ws[WS_GN + iN * 3 + j], gts * dir * invc);
    }
  }
}

// ---------------- per-node: loss terms, preds, center sums ----------------
__global__ void k_node2(const int* batch, float* ws) {
  int n = blockIdx.x * blockDim.x + threadIdx.x;
  if (n >= Nn) return;
  int b = batch[n];
  float sig = ws[WS_SIG + b];
#pragma unroll
  for (int j = 0; j < 3; ++j) {
    float s = ws[WS_SN + n * 3 + j], g = ws[WS_GN + n * 3 + j];
    float d = s - g / sig;
    atomicAdd(&ws[WS_BSUM + b * 3 + j], d * d);
    float pr = ws[WS_PERT + n * 3 + j] + s / sig;
    ws[WS_PREDS + n * 3 + j] = pr;
    atomicAdd(&ws[WS_CENTER + b * 3 + j], pr);
  }
}

// ---------------- per-node: global min/max of dc ----------------
__global__ void k_minmax(const int* batch, const int* num_atoms, float* ws) {
  int n = blockIdx.x * blockDim.x + threadIdx.x;
  int lane = threadIdx.x & 63, wid = threadIdx.x >> 6;
  float mx[3], mn[3];
  if (n < Nn) {
    int b = batch[n];
    float na = (float)num_atoms[b];
#pragma unroll
    for (int j = 0; j < 3; ++j) {
      float v = ws[WS_PREDS + n * 3 + j] - ws[WS_CENTER + b * 3 + j] / na;
      mx[j] = v; mn[j] = v;
    }
  } else {
#pragma unroll
    for (int j = 0; j < 3; ++j) { mx[j] = -3.0e38f; mn[j] = 3.0e38f; }
  }
#pragma unroll
  for (int off = 32; off >= 1; off >>= 1) {
#pragma unroll
    for (int j = 0; j < 3; ++j) {
      mx[j] = fmaxf(mx[j], __shfl_xor(mx[j], off));
      mn[j] = fminf(mn[j], __shfl_xor(mn[j], off));
    }
  }
  __shared__ float smx[4][3], smn[4][3];
  if (lane == 0) {
#pragma unroll
    for (int j = 0; j < 3; ++j) { smx[wid][j] = mx[j]; smn[wid][j] = mn[j]; }
  }
  __syncthreads();
  if (threadIdx.x == 0) {
#pragma unroll
    for (int j = 0; j < 3; ++j) {
      float M = fmaxf(fmaxf(smx[0][j], smx[1][j]), fmaxf(smx[2][j], smx[3][j]));
      float m = fminf(fminf(smn[0][j], smn[1][j]), fminf(smn[2][j], smn[3][j]));
      atomicMaxFloat(&ws[WS_MINMAX + j], M);
      atomicMinFloat(&ws[WS_MINMAX + 3 + j], m);
    }
  }
}

// ---------------- finalize (parallel over batches) ----------------
__global__ void k_final(const int* num_atoms, const float* ws, float* out) {
  int t = threadIdx.x;  // 128 threads
  float loss = 0.f;
  if (t < Bb) {
    float na = (float)num_atoms[t];
    loss = (ws[WS_BSUM + t * 3] + ws[WS_BSUM + t * 3 + 1] + ws[WS_BSUM + t * 3 + 2]) / na;
  }
#pragma unroll
  for (int off = 32; off >= 1; off >>= 1) loss += __shfl_xor(loss, off);
  __shared__ float s2[2];
  if ((t & 63) == 0) s2[t >> 6] = loss;
  __syncthreads();
  if (t == 0) {
    float L = (s2[0] + s2[1]) / (3.0f * (float)Bb);
    float pbs = fabsf(ws[WS_MINMAX + 0] + ws[WS_MINMAX + 3]) +
                fabsf(ws[WS_MINMAX + 1] + ws[WS_MINMAX + 4]) +
                fabsf(ws[WS_MINMAX + 2] + ws[WS_MINMAX + 5]);
    out[0] = L;
    out[1] = pbs;
  }
}

extern "C" void kernel_launch(void* const* d_in, const int* in_sizes, int n_in,
                              void* d_out, int out_size, void* d_ws, size_t ws_size,
                              hipStream_t stream) {
  const float* latents = (const float*)d_in[0];
  const float* gtf     = (const float*)d_in[1];
  const float* lengths = (const float*)d_in[2];
  const float* angles  = (const float*)d_in[3];
  const float* noise   = (const float*)d_in[4];
  const float* sigmas  = (const float*)d_in[5];
  const float* aemb    = (const float*)d_in[6];
  const float* rbfW    = (const float*)d_in[7];
  const float* rbfb    = (const float*)d_in[8];
  const float* bbW     = (const float*)d_in[9];
  const float* bbb     = (const float*)d_in[10];
  const float* scW0    = (const float*)d_in[11];
  const float* scb0    = (const float*)d_in[12];
  const float* scW1    = (const float*)d_in[13];
  const float* scb1    = (const float*)d_in[14];
  const float* scW2    = (const float*)d_in[15];
  const float* scb2    = (const float*)d_in[16];
  const int* num_atoms = (const int*)d_in[17];
  const int* atype     = (const int*)d_in[18];
  const int* batch     = (const int*)d_in[19];
  const int* ei        = (const int*)d_in[20];
  const int* toj       = (const int*)d_in[21];
  const int* tsteps    = (const int*)d_in[22];
  float* ws = (float*)d_ws;
  float* out = (float*)d_out;
  unsigned short* w0t = (unsigned short*)(ws + WS_W0T_F);
  unsigned short* w1t = (unsigned short*)(ws + WS_W1T_F);

  hipLaunchKernelGGL(k_pre, dim3(1814), dim3(256), 0, stream,
                     lengths, angles, sigmas, tsteps, aemb, bbW, rbfW, rbfb, bbb,
                     latents, scW0, scb0, scW1, w0t, w1t, ws);
  hipLaunchKernelGGL(k_node, dim3(50), dim3(256), 0, stream, gtf, noise, batch, ws);
  hipLaunchKernelGGL(k_edge, dim3(Ee / TE), dim3(512), 0, stream,
                     ei, toj, batch, atype, w0t, w1t, scb1, scW2, scb2, ws);
  hipLaunchKernelGGL(k_node2, dim3(50), dim3(256), 0, stream, batch, ws);
  hipLaunchKernelGGL(k_minmax, dim3(50), dim3(256), 0, stream, batch, num_atoms, ws);
  hipLaunchKernelGGL(k_final, dim3(1), dim3(128), 0, stream, num_atoms, ws, out);
}

// Round 10
// 356.493 us; speedup vs baseline: 1.0947x; 1.0108x over previous
//
#include <hip/hip_runtime.h>
#include <hip/hip_bf16.h>

// ---------------- problem constants ----------------
namespace {
constexpr int Bb = 128, Nn = 12800, Ee = 262144;
constexpr int LAT = 256, HID = 128, FCH = 512, NRBF = 16;
constexpr int TE = 64; // edges per block in edge kernel (divides 2048 = edges/graph)

// workspace offsets (floats)
constexpr int WS_L      = 0;        // B*9
constexpr int WS_LI     = 1152;     // B*9
constexpr int WS_SIG    = 2304;     // B
constexpr int WS_RBFW2  = 2432;     // 16*128
constexpr int WS_CVEC   = 4480;     // 128
constexpr int WS_HB     = 4608;     // 100*128
constexpr int WS_LATP   = 17408;    // B*512
constexpr int WS_PERT   = 82944;    // N*3
constexpr int WS_ALIGN  = 121344;   // N*3
constexpr int WS_SN     = 159744;   // N*3 (atomic)
constexpr int WS_GN     = 198144;   // N*3 (atomic)
constexpr int WS_PREDS  = 236544;   // N*3
constexpr int WS_BSUM   = 274944;   // B*3 (atomic)
constexpr int WS_CENTER = 275328;   // B*3 (atomic)
constexpr int WS_MINMAX = 275712;   // 6   (max x3, min x3)
// bf16 fragment-tiled weights (stored as ushort), float-index base:
constexpr int WS_W0T_F  = 276000;   // ushort[512*128]  (= 32768 floats)
constexpr int WS_W1T_F  = 308768;   // ushort[512*512]  (= 131072 floats)
}

typedef short bf16x8 __attribute__((ext_vector_type(8)));
typedef float f32x4 __attribute__((ext_vector_type(4)));

static __device__ __forceinline__ unsigned short f2bf(float f) {
  unsigned int u = __float_as_uint(f);
  unsigned int r = (u + 0x7fffu + ((u >> 16) & 1u)) >> 16;
  return (unsigned short)r;
}
// packed pair: returns uint with bf16(a) in low16, bf16(b) in high16
static __device__ __forceinline__ unsigned int pk2bf(float a, float b) {
  __hip_bfloat162 h2 = __float22bfloat162_rn(make_float2(a, b));
  return *reinterpret_cast<unsigned int*>(&h2);
}

static __device__ __forceinline__ void atomicMaxFloat(float* addr, float val) {
  int* ai = reinterpret_cast<int*>(addr);
  int old = *ai;
  while (__int_as_float(old) < val) {
    int assumed = old;
    old = atomicCAS(ai, assumed, __float_as_int(val));
    if (old == assumed) break;
  }
}
static __device__ __forceinline__ void atomicMinFloat(float* addr, float val) {
  int* ai = reinterpret_cast<int*>(addr);
  int old = *ai;
  while (__int_as_float(old) > val) {
    int assumed = old;
    old = atomicCAS(ai, assumed, __float_as_int(val));
    if (old == assumed) break;
  }
}

// ---------------- fused prologue: all mutually-independent prep work ----------------
__global__ __launch_bounds__(256) void k_pre(
    const float* lengths, const float* angles, const float* sigmas, const int* tsteps,
    const float* aemb, const float* bbW, const float* rbfW, const float* rbfb,
    const float* bbb, const float* latents, const float* scW0, const float* scb0,
    const float* scW1, unsigned short* w0t, unsigned short* w1t, float* ws) {
  const int blk = blockIdx.x, t = threadIdx.x;
  if (blk < 304) {
    int gid = blk * 256 + t;
    if (gid < 2 * Nn * 3) ws[WS_SN + gid] = 0.f;
    else if (gid < 2 * Nn * 3 + 2 * Bb * 3) ws[WS_BSUM + (gid - 2 * Nn * 3)] = 0.f;
    else if (gid < 2 * Nn * 3 + 2 * Bb * 3 + 3) ws[WS_MINMAX + (gid - 2 * Nn * 3 - 2 * Bb * 3)] = -3.0e38f;
    else if (gid < 2 * Nn * 3 + 2 * Bb * 3 + 6) ws[WS_MINMAX + (gid - 2 * Nn * 3 - 2 * Bb * 3)] = 3.0e38f;
  } else if (blk == 304) {
    int b = t;
    if (b >= Bb) return;
    float a = lengths[b * 3 + 0], bl = lengths[b * 3 + 1], c = lengths[b * 3 + 2];
    const float d2r = 0.017453292519943295f;
    float al = angles[b * 3 + 0] * d2r, be = angles[b * 3 + 1] * d2r, ga = angles[b * 3 + 2] * d2r;
    float ca = cosf(al), cb = cosf(be), cg = cosf(ga), sa = sinf(al), sb = sinf(be);
    float val = (ca * cb - cg) / (sa * sb);
    val = fminf(1.f, fmaxf(-1.f, val));
    float gs = acosf(val);
    float L[3][3];
    L[0][0] = a * sb;              L[0][1] = 0.f;                L[0][2] = a * cb;
    L[1][0] = -bl * sa * cosf(gs); L[1][1] = bl * sa * sinf(gs); L[1][2] = bl * ca;
    L[2][0] = 0.f;                 L[2][1] = 0.f;                L[2][2] = c;
    float det = L[0][0] * (L[1][1] * L[2][2] - L[1][2] * L[2][1])
              - L[0][1] * (L[1][0] * L[2][2] - L[1][2] * L[2][0])
              + L[0][2] * (L[1][0] * L[2][1] - L[1][1] * L[2][0]);
    float id = 1.f / det;
    float inv[3][3];
    inv[0][0] =  (L[1][1]*L[2][2] - L[1][2]*L[2][1]) * id;
    inv[0][1] = -(L[0][1]*L[2][2] - L[0][2]*L[2][1]) * id;
    inv[0][2] =  (L[0][1]*L[1][2] - L[0][2]*L[1][1]) * id;
    inv[1][0] = -(L[1][0]*L[2][2] - L[1][2]*L[2][0]) * id;
    inv[1][1] =  (L[0][0]*L[2][2] - L[0][2]*L[2][0]) * id;
    inv[1][2] = -(L[0][0]*L[1][2] - L[0][2]*L[1][0]) * id;
    inv[2][0] =  (L[1][0]*L[2][1] - L[1][1]*L[2][0]) * id;
    inv[2][1] = -(L[0][0]*L[2][1] - L[0][1]*L[2][0]) * id;
    inv[2][2] =  (L[0][0]*L[1][1] - L[0][1]*L[1][0]) * id;
    for (int i = 0; i < 3; ++i)
      for (int j = 0; j < 3; ++j) {
        ws[WS_L + b * 9 + i * 3 + j] = L[i][j];
        ws[WS_LI + b * 9 + i * 3 + j] = inv[i][j];
      }
    ws[WS_SIG + b] = sigmas[tsteps[b]];
  } else if (blk < 405) {
    int tile = blk - 305;
    if (t < HID) {
      float acc = 0.f;
      for (int k = 0; k < HID; ++k) acc += aemb[tile * HID + k] * bbW[k * HID + t];
      ws[WS_HB + tile * HID + t] = acc;
    }
  } else if (blk == 405) {
    if (t < HID) {
      float accs[NRBF];
#pragma unroll
      for (int k = 0; k < NRBF; ++k) accs[k] = 0.f;
      float accb = 0.f;
      for (int m = 0; m < HID; ++m) {
        float w = bbW[m * HID + t];
#pragma unroll
        for (int k = 0; k < NRBF; ++k) accs[k] += rbfW[k * HID + m] * w;
        accb += rbfb[m] * w;
      }
#pragma unroll
      for (int k = 0; k < NRBF; ++k) ws[WS_RBFW2 + k * HID + t] = accs[k];
      ws[WS_CVEC + t] = accb + bbb[t];
    }
  } else if (blk < 534) {
    int b = blk - 406;
    __shared__ float lat[LAT];
    lat[t] = latents[b * LAT + t];
    __syncthreads();
    int c0 = 2 * t;
    float a0 = 0.f, a1 = 0.f;
    for (int m = 0; m < LAT; ++m) {
      float2 w = *reinterpret_cast<const float2*>(scW0 + (HID + m) * FCH + c0);
      float lm = lat[m];
      a0 += lm * w.x;
      a1 += lm * w.y;
    }
    ws[WS_LATP + b * FCH + c0] = a0 + scb0[c0];
    ws[WS_LATP + b * FCH + c0 + 1] = a1 + scb0[c0 + 1];
  } else if (blk < 790) {
    // cvtW0: coalesced read scW0[tid] (tid = k*512+col, k<128), scattered 2B write
    int tid = (blk - 534) * 256 + t;   // 65536
    int col = tid & 511, k = tid >> 9;
    int id = (((col >> 4) * 4 + (k >> 5)) * 64 + ((k & 31) >> 3) * 16 + (col & 15)) * 8 + (k & 7);
    w0t[id] = f2bf(scW0[tid]);
  } else {
    // cvtW1: coalesced read scW1[tid] (tid = k*512+col, k<512), scattered 2B write
    int tid = (blk - 790) * 256 + t;   // 262144
    int col = tid & 511, k = tid >> 9;
    int id = (((col >> 4) * 16 + (k >> 5)) * 64 + ((k & 31) >> 3) * 16 + (col & 15)) * 8 + (k & 7);
    w1t[id] = f2bf(scW1[tid]);
  }
}

// ---------------- per-node geometry ----------------
__global__ void k_node(const float* frac, const float* noise, const int* batch, float* ws) {
  int n = blockIdx.x * blockDim.x + threadIdx.x;
  if (n >= Nn) return;
  int b = batch[n];
  float L[9], Li[9];
#pragma unroll
  for (int i = 0; i < 9; ++i) { L[i] = ws[WS_L + b * 9 + i]; Li[i] = ws[WS_LI + b * 9 + i]; }
  float f0 = frac[n * 3], f1 = frac[n * 3 + 1], f2 = frac[n * 3 + 2];
  float cg[3], p0[3], fp[3], pe[3], fg[3], fd[3];
#pragma unroll
  for (int j = 0; j < 3; ++j) cg[j] = f0 * L[j] + f1 * L[3 + j] + f2 * L[6 + j];
  float sig = ws[WS_SIG + b];
#pragma unroll
  for (int j = 0; j < 3; ++j) p0[j] = cg[j] + sig * noise[n * 3 + j];
#pragma unroll
  for (int j = 0; j < 3; ++j) {
    float v = p0[0] * Li[j] + p0[1] * Li[3 + j] + p0[2] * Li[6 + j];
    fp[j] = v - floorf(v);
  }
#pragma unroll
  for (int j = 0; j < 3; ++j) pe[j] = fp[0] * L[j] + fp[1] * L[3 + j] + fp[2] * L[6 + j];
#pragma unroll
  for (int j = 0; j < 3; ++j) fg[j] = cg[0] * Li[j] + cg[1] * Li[3 + j] + cg[2] * Li[6 + j];
#pragma unroll
  for (int j = 0; j < 3; ++j) { float d = fg[j] - fp[j]; fd[j] = d - rintf(d); }
#pragma unroll
  for (int j = 0; j < 3; ++j) {
    ws[WS_PERT + n * 3 + j] = pe[j];
    ws[WS_ALIGN + n * 3 + j] = pe[j] + fd[0] * L[j] + fd[1] * L[3 + j] + fd[2] * L[6 + j];
  }
}

// ---------------- the big fused MFMA edge kernel (transposed compute) ----------------
// We compute D[wcol][edge] = mfma(A = W^T fragment, B = act^T fragment).
// The stored weight tiles (w0t/w1t) already ARE valid A-fragments:
//   A-frag lane l holds A[l&15][8*(l>>4)+e]  ==  W[k][col] with col = l&15.
// Activations live in LDS in B-fragment tile order:
//   tile (kTile, eT) of 32 k x 16 edges at byte (kTile*4+eT)*1024 + lane*16,
//   lane = (edge&15) + 16*((k&31)>>3), byte-in-lane = (k&7)*2.
// => every ds_read is lane*16B contiguous (2-way free), no XOR swizzle needed.
// D layout: col = l&15 = edge-in-tile, row = wcol-in-tile = (l>>4)*4 + r.
// Tile: 64 edges x 512 cols, 8 waves; wave wv owns wcols [wv*64, wv*64+64).
// LDS ~68.5 KB -> 2 blocks/CU. Alias plan inside s_hh (64KB):
//   s_efT  bytes [0, 16384)      B-frag tiles (4 kTiles x 4 eT)  (Phase B->C)
//   rbfw2  bytes [16384, 24576)  f32[16][128]
//   cvec   bytes [24576, 25088)  f32[128]
//   rbfE   bytes [25088, 29184)  f32[64][16]
// all dead before the GEMM1 epilogue overwrites s_hhT [0,64K) (barrier-enforced).
__global__ __launch_bounds__(512, 4) void k_edge(
    const int* ei, const int* toj, const int* batch, const int* atype,
    const unsigned short* w0t, const unsigned short* w1t,
    const float* scb1, const float* scW2, const float* scb2, float* ws) {
  __shared__ unsigned short s_hh[TE * FCH];   // 64 KB, B-frag tile order (16 kT x 4 eT)
  __shared__ float s_dvec[TE][3];
  __shared__ float s_dist[TE], s_gtd[TE];
  __shared__ int s_tj[TE], s_ti[TE];
  __shared__ float s_wsum[8][TE];             // 2 KB

  char* s_hh_b = (char*)s_hh;
  char* s_ef_b = s_hh_b;                          // alias: 4 kT x 4 eT x 1KB
  float* s_rbfw2 = (float*)(s_hh_b + 16384);      // [16][128] f32 (8 KB)
  float* s_cvec  = (float*)(s_hh_b + 24576);      // [128] f32 (512 B)
  float* s_rbfE  = (float*)(s_hh_b + 25088);      // [64][16] f32 (4 KB)

  const int t = threadIdx.x;
  const int e0 = blockIdx.x * TE;
  const int b0 = batch[ei[e0]];

  // ---- Phase A: stage rbfW2+cvec to LDS; per-edge geometry + rbf (t<64)
  {
    const float4* src = (const float4*)(ws + WS_RBFW2);  // 512 float4
    float4* dst = (float4*)s_rbfw2;
    dst[t] = src[t];
    if (t < 32) ((float4*)s_cvec)[t] = ((const float4*)(ws + WS_CVEC))[t];
  }
  if (t < TE) {
    int e = e0 + t;
    int jn = ei[e], iN = ei[Ee + e];
    int b = batch[jn];
    float tx = (float)toj[e * 3], ty = (float)toj[e * 3 + 1], tz = (float)toj[e * 3 + 2];
    const float* L = ws + WS_L + b * 9;
    float dv[3], gv[3];
#pragma unroll
    for (int j = 0; j < 3; ++j) {
      float off = tx * L[j] + ty * L[3 + j] + tz * L[6 + j];
      dv[j] = ws[WS_PERT + iN * 3 + j] - ws[WS_PERT + jn * 3 + j] - off;
      gv[j] = ws[WS_ALIGN + iN * 3 + j] - ws[WS_ALIGN + jn * 3 + j] - off;
    }
    float dist = sqrtf(dv[0] * dv[0] + dv[1] * dv[1] + dv[2] * dv[2]);
    float gtd = sqrtf(gv[0] * gv[0] + gv[1] * gv[1] + gv[2] * gv[2]);
#pragma unroll
    for (int j = 0; j < 3; ++j) s_dvec[t][j] = dv[j];
    s_dist[t] = dist;
    s_gtd[t] = gtd;
    s_tj[t] = atype[jn]; s_ti[t] = atype[iN];
    const float step = 7.0f / 15.0f;
#pragma unroll
    for (int k = 0; k < NRBF; ++k) {
      float d = dist - (float)k * step;
      s_rbfE[t * NRBF + k] = __expf(-10.f * d * d);
    }
  }
  __syncthreads();

  // ---- Phase B: ef = silu(hb[tj]+hb[ti]+rbf@rbfW2+cvec) -> s_efT (B-frag tiles)
  {
    int e = t >> 3;              // 0..63 (edge in tile)
    int c0 = (t & 7) * 16;       // 16 hid cols per thread
    int tj = s_tj[e], ti = s_ti[e];
    float4 rb4[4];
#pragma unroll
    for (int q = 0; q < 4; ++q) rb4[q] = ((const float4*)(s_rbfE + e * NRBF))[q];
    float rb[NRBF] = {rb4[0].x, rb4[0].y, rb4[0].z, rb4[0].w,
                      rb4[1].x, rb4[1].y, rb4[1].z, rb4[1].w,
                      rb4[2].x, rb4[2].y, rb4[2].z, rb4[2].w,
                      rb4[3].x, rb4[3].y, rb4[3].z, rb4[3].w};
    float4 z4[4];
#pragma unroll
    for (int q = 0; q < 4; ++q) {
      float4 a = *(const float4*)(ws + WS_HB + tj * HID + c0 + q * 4);
      float4 bq = *(const float4*)(ws + WS_HB + ti * HID + c0 + q * 4);
      float4 cv = ((const float4*)s_cvec)[c0 / 4 + q];
      z4[q].x = a.x + bq.x + cv.x; z4[q].y = a.y + bq.y + cv.y;
      z4[q].z = a.z + bq.z + cv.z; z4[q].w = a.w + bq.w + cv.w;
    }
#pragma unroll
    for (int k = 0; k < NRBF; ++k) {
      float rbk = rb[k];
#pragma unroll
      for (int q = 0; q < 4; ++q) {
        float4 wv4 = ((const float4*)s_rbfw2)[k * 32 + c0 / 4 + q];
        z4[q].x += rbk * wv4.x; z4[q].y += rbk * wv4.y;
        z4[q].z += rbk * wv4.z; z4[q].w += rbk * wv4.w;
      }
    }
    float sv[16];
#pragma unroll
    for (int q = 0; q < 4; ++q) {
      sv[q * 4 + 0] = z4[q].x / (1.f + __expf(-z4[q].x));
      sv[q * 4 + 1] = z4[q].y / (1.f + __expf(-z4[q].y));
      sv[q * 4 + 2] = z4[q].z / (1.f + __expf(-z4[q].z));
      sv[q * 4 + 3] = z4[q].w / (1.f + __expf(-z4[q].w));
    }
    unsigned int w[8];
#pragma unroll
    for (int p = 0; p < 8; ++p) w[p] = pk2bf(sv[2 * p], sv[2 * p + 1]);
    // Two 16B stores, one per hid-octet o: hid = c0 + 8o .. c0 + 8o + 7
    int eT = e >> 4, el = e & 15;
#pragma unroll
    for (int o = 0; o < 2; ++o) {
      int hid = c0 + 8 * o;
      int kt = hid >> 5;
      int oct = (hid & 31) >> 3;
      int addr = (kt * 4 + eT) * 1024 + (el + 16 * oct) * 16;
      uint4 val = {w[4 * o + 0], w[4 * o + 1], w[4 * o + 2], w[4 * o + 3]};
      *(uint4*)(s_ef_b + addr) = val;
    }
  }
  __syncthreads();

  const int lane = t & 63;
  const int wv = t >> 6;        // 0..7
  const int el = lane & 15;     // edge-in-tile (D col / B-frag edge)
  const int q  = lane >> 4;     // k-octet group

  // ---- Phase C: GEMM1^T  hh^T = relu(W0a^T @ ef^T + latp), -> s_hhT (B-frag tiles)
  {
    f32x4 acc[4][4];  // [m = wcolTile][n = edgeTile]
#pragma unroll
    for (int m = 0; m < 4; ++m)
#pragma unroll
      for (int n = 0; n < 4; ++n) acc[m][n] = (f32x4){0.f, 0.f, 0.f, 0.f};
    const unsigned short* w0base = w0t + (size_t)(wv * 4) * 4 * 512 + lane * 8;
#pragma unroll
    for (int kt = 0; kt < 4; ++kt) {
      bf16x8 aw[4];
#pragma unroll
      for (int m = 0; m < 4; ++m)
        aw[m] = *(const bf16x8*)(w0base + (size_t)(m * 4 + kt) * 512);
      bf16x8 bf[4];
#pragma unroll
      for (int n = 0; n < 4; ++n)
        bf[n] = *(const bf16x8*)(s_ef_b + (kt * 4 + n) * 1024 + lane * 16);
      __builtin_amdgcn_s_setprio(1);
#pragma unroll
      for (int n = 0; n < 4; ++n)
#pragma unroll
        for (int m = 0; m < 4; ++m)
          acc[m][n] = __builtin_amdgcn_mfma_f32_16x16x32_bf16(aw[m], bf[n], acc[m][n], 0, 0, 0);
      __builtin_amdgcn_s_setprio(0);
    }
    __syncthreads();   // ALL s_efT reads complete before s_hhT overwrites the alias
    // Epilogue: lane holds D[wcol = m*16 + q*4 + r][edge = n*16 + el].
    // Write as GEMM2 B-frag: kTile = wcol>>5, lane' = el + 16*((wcol&31)>>3),
    // bytes ((wcol&7)*2) .. : thread's r=0..3 are 4 consecutive bf16 = 8B chunk.
#pragma unroll
    for (int m = 0; m < 4; ++m) {
      float4 lp = *(const float4*)(ws + WS_LATP + b0 * FCH + wv * 64 + m * 16 + q * 4);
#pragma unroll
      for (int n = 0; n < 4; ++n) {
        f32x4 v = acc[m][n];
        float h0 = fmaxf(v[0] + lp.x, 0.f);
        float h1 = fmaxf(v[1] + lp.y, 0.f);
        float h2 = fmaxf(v[2] + lp.z, 0.f);
        float h3 = fmaxf(v[3] + lp.w, 0.f);
        uint2 val = {pk2bf(h0, h1), pk2bf(h2, h3)};
        int kT = wv * 2 + (m >> 1);
        int oct = (m & 1) * 2 + (q >> 1);
        int addr = (kT * 4 + n) * 1024 + (el + 16 * oct) * 16 + (q & 1) * 8;
        *(uint2*)(s_hh_b + addr) = val;
      }
    }
  }
  __syncthreads();

  // ---- Phase D: GEMM2^T + fused score reduction
  {
    f32x4 acc[4][4];  // [m = w1colTile][n = edgeTile]
#pragma unroll
    for (int m = 0; m < 4; ++m)
#pragma unroll
      for (int n = 0; n < 4; ++n) acc[m][n] = (f32x4){0.f, 0.f, 0.f, 0.f};
    const unsigned short* w1base = w1t + (size_t)(wv * 4) * 16 * 512 + lane * 8;
#pragma unroll 4
    for (int kt = 0; kt < 16; ++kt) {
      bf16x8 aw[4];
#pragma unroll
      for (int m = 0; m < 4; ++m)
        aw[m] = *(const bf16x8*)(w1base + (size_t)(m * 16 + kt) * 512);
      bf16x8 bf[4];
#pragma unroll
      for (int n = 0; n < 4; ++n)
        bf[n] = *(const bf16x8*)(s_hh_b + (kt * 4 + n) * 1024 + lane * 16);
      __builtin_amdgcn_s_setprio(1);
#pragma unroll
      for (int n = 0; n < 4; ++n)
#pragma unroll
        for (int m = 0; m < 4; ++m)
          acc[m][n] = __builtin_amdgcn_mfma_f32_16x16x32_bf16(aw[m], bf[n], acc[m][n], 0, 0, 0);
      __builtin_amdgcn_s_setprio(0);
    }
    // hh1 = relu(acc + b1); p[edge] += hh1 * W2, reduced over w1cols
    float p[4] = {0.f, 0.f, 0.f, 0.f};   // per edgeTile n
#pragma unroll
    for (int m = 0; m < 4; ++m) {
      int colb = wv * 64 + m * 16 + q * 4;
      float4 b1v = *(const float4*)(scb1 + colb);
      float4 w2v = *(const float4*)(scW2 + colb);
#pragma unroll
      for (int n = 0; n < 4; ++n) {
        f32x4 v = acc[m][n];
        p[n] += fmaxf(v[0] + b1v.x, 0.f) * w2v.x;
        p[n] += fmaxf(v[1] + b1v.y, 0.f) * w2v.y;
        p[n] += fmaxf(v[2] + b1v.z, 0.f) * w2v.z;
        p[n] += fmaxf(v[3] + b1v.w, 0.f) * w2v.w;
      }
    }
    // reduce over q (lane bits 4..5)
#pragma unroll
    for (int n = 0; n < 4; ++n) {
      float x = p[n];
      x += __shfl_xor(x, 16);
      x += __shfl_xor(x, 32);
      p[n] = x;
    }
    if (lane < 16) {
#pragma unroll
      for (int n = 0; n < 4; ++n) s_wsum[wv][n * 16 + el] = p[n];
    }
  }
  __syncthreads();

  // ---- Phase E: segment-mean scatter (threads 0..63)
  if (t < TE) {
    int e = e0 + t;
    float score = scb2[0];
#pragma unroll
    for (int w = 0; w < 8; ++w) score += s_wsum[w][t];
    int jn = ei[e], iN = ei[Ee + e];
    int s = e;
    while (s > 0 && ei[s - 1] == jn && ei[Ee + s - 1] == iN) --s;
    int en = e;
    while (en + 1 < Ee && ei[en + 1] == jn && ei[Ee + en + 1] == iN) ++en;
    float invc = 1.f / (float)(en - s + 1);
    float dist = s_dist[t];
    float denom = dist + 1e-8f;
    float gts = s_gtd[t] - dist;
#pragma unroll
    for (int j = 0; j < 3; ++j) {
      float dir = s_dvec[t][j] / denom;
      atomicAdd(&ws[WS_SN + iN * 3 + j], score * dir * invc);
      atomicAdd(&ws[WS_GN + iN * 3 + j], gts * dir * invc);
    }
  }
}

// ---------------- per-node: loss terms, preds, center sums ----------------
__global__ void k_node2(const int* batch, float* ws) {
  int n = blockIdx.x * blockDim.x + threadIdx.x;
  if (n >= Nn) return;
  int b = batch[n];
  float sig = ws[WS_SIG + b];
#pragma unroll
  for (int j = 0; j < 3; ++j) {
    float s = ws[WS_SN + n * 3 + j], g = ws[WS_GN + n * 3 + j];
    float d = s - g / sig;
    atomicAdd(&ws[WS_BSUM + b * 3 + j], d * d);
    float pr = ws[WS_PERT + n * 3 + j] + s / sig;
    ws[WS_PREDS + n * 3 + j] = pr;
    atomicAdd(&ws[WS_CENTER + b * 3 + j], pr);
  }
}

// ---------------- per-node: global min/max of dc ----------------
__global__ void k_minmax(const int* batch, const int* num_atoms, float* ws) {
  int n = blockIdx.x * blockDim.x + threadIdx.x;
  int lane = threadIdx.x & 63, wid = threadIdx.x >> 6;
  float mx[3], mn[3];
  if (n < Nn) {
    int b = batch[n];
    float na = (float)num_atoms[b];
#pragma unroll
    for (int j = 0; j < 3; ++j) {
      float v = ws[WS_PREDS + n * 3 + j] - ws[WS_CENTER + b * 3 + j] / na;
      mx[j] = v; mn[j] = v;
    }
  } else {
#pragma unroll
    for (int j = 0; j < 3; ++j) { mx[j] = -3.0e38f; mn[j] = 3.0e38f; }
  }
#pragma unroll
  for (int off = 32; off >= 1; off >>= 1) {
#pragma unroll
    for (int j = 0; j < 3; ++j) {
      mx[j] = fmaxf(mx[j], __shfl_xor(mx[j], off));
      mn[j] = fminf(mn[j], __shfl_xor(mn[j], off));
    }
  }
  __shared__ float smx[4][3], smn[4][3];
  if (lane == 0) {
#pragma unroll
    for (int j = 0; j < 3; ++j) { smx[wid][j] = mx[j]; smn[wid][j] = mn[j]; }
  }
  __syncthreads();
  if (threadIdx.x == 0) {
#pragma unroll
    for (int j = 0; j < 3; ++j) {
      float M = fmaxf(fmaxf(smx[0][j], smx[1][j]), fmaxf(smx[2][j], smx[3][j]));
      float m = fminf(fminf(smn[0][j], smn[1][j]), fminf(smn[2][j], smn[3][j]));
      atomicMaxFloat(&ws[WS_MINMAX + j], M);
      atomicMinFloat(&ws[WS_MINMAX + 3 + j], m);
    }
  }
}

// ---------------- finalize (parallel over batches) ----------------
__global__ void k_final(const int* num_atoms, const float* ws, float* out) {
  int t = threadIdx.x;  // 128 threads
  float loss = 0.f;
  if (t < Bb) {
    float na = (float)num_atoms[t];
    loss = (ws[WS_BSUM + t * 3] + ws[WS_BSUM + t * 3 + 1] + ws[WS_BSUM + t * 3 + 2]) / na;
  }
#pragma unroll
  for (int off = 32; off >= 1; off >>= 1) loss += __shfl_xor(loss, off);
  __shared__ float s2[2];
  if ((t & 63) == 0) s2[t >> 6] = loss;
  __syncthreads();
  if (t == 0) {
    float L = (s2[0] + s2[1]) / (3.0f * (float)Bb);
    float pbs = fabsf(ws[WS_MINMAX + 0] + ws[WS_MINMAX + 3]) +
                fabsf(ws[WS_MINMAX + 1] + ws[WS_MINMAX + 4]) +
                fabsf(ws[WS_MINMAX + 2] + ws[WS_MINMAX + 5]);
    out[0] = L;
    out[1] = pbs;
  }
}

extern "C" void kernel_launch(void* const* d_in, const int* in_sizes, int n_in,
                              void* d_out, int out_size, void* d_ws, size_t ws_size,
                              hipStream_t stream) {
  const float* latents = (const float*)d_in[0];
  const float* gtf     = (const float*)d_in[1];
  const float* lengths = (const float*)d_in[2];
  const float* angles  = (const float*)d_in[3];
  const float* noise   = (const float*)d_in[4];
  const float* sigmas  = (const float*)d_in[5];
  const float* aemb    = (const float*)d_in[6];
  const float* rbfW    = (const float*)d_in[7];
  const float* rbfb    = (const float*)d_in[8];
  const float* bbW     = (const float*)d_in[9];
  const float* bbb     = (const float*)d_in[10];
  const float* scW0    = (const float*)d_in[11];
  const float* scb0    = (const float*)d_in[12];
  const float* scW1    = (const float*)d_in[13];
  const float* scb1    = (const float*)d_in[14];
  const float* scW2    = (const float*)d_in[15];
  const float* scb2    = (const float*)d_in[16];
  const int* num_atoms = (const int*)d_in[17];
  const int* atype     = (const int*)d_in[18];
  const int* batch     = (const int*)d_in[19];
  const int* ei        = (const int*)d_in[20];
  const int* toj       = (const int*)d_in[21];
  const int* tsteps    = (const int*)d_in[22];
  float* ws = (float*)d_ws;
  float* out = (float*)d_out;
  unsigned short* w0t = (unsigned short*)(ws + WS_W0T_F);
  unsigned short* w1t = (unsigned short*)(ws + WS_W1T_F);

  hipLaunchKernelGGL(k_pre, dim3(1814), dim3(256), 0, stream,
                     lengths, angles, sigmas, tsteps, aemb, bbW, rbfW, rbfb, bbb,
                     latents, scW0, scb0, scW1, w0t, w1t, ws);
  hipLaunchKernelGGL(k_node, dim3(50), dim3(256), 0, stream, gtf, noise, batch, ws);
  hipLaunchKernelGGL(k_edge, dim3(Ee / TE), dim3(512), 0, stream,
                     ei, toj, batch, atype, w0t, w1t, scb1, scW2, scb2, ws);
  hipLaunchKernelGGL(k_node2, dim3(50), dim3(256), 0, stream, batch, ws);
  hipLaunchKernelGGL(k_minmax, dim3(50), dim3(256), 0, stream, batch, num_atoms, ws);
  hipLaunchKernelGGL(k_final, dim3(1), dim3(128), 0, stream, num_atoms, ws, out);
}

// Round 11
// 323.003 us; speedup vs baseline: 1.2082x; 1.1037x over previous
//
#include <hip/hip_runtime.h>
#include <hip/hip_bf16.h>

// ---------------- problem constants ----------------
namespace {
constexpr int Bb = 128, Nn = 12800, Ee = 262144;
constexpr int LAT = 256, HID = 128, FCH = 512, NRBF = 16;
constexpr int TE = 64;       // edges per block (divides 2048 = edges/graph)
constexpr int TSTRIDE = 1040; // activation-tile stride in bytes (1024 + 16 pad: breaks
                              // the 256-B bank aliasing of B-frag writes across tiles)

// workspace offsets (floats)
constexpr int WS_L      = 0;        // B*9
constexpr int WS_LI     = 1152;     // B*9
constexpr int WS_SIG    = 2304;     // B
constexpr int WS_RBFW2  = 2432;     // 16*128
constexpr int WS_CVEC   = 4480;     // 128
constexpr int WS_HB     = 4608;     // 100*128
constexpr int WS_LATP   = 17408;    // B*512
constexpr int WS_PERT   = 82944;    // N*3
constexpr int WS_ALIGN  = 121344;   // N*3
constexpr int WS_SN     = 159744;   // N*3 (atomic)
constexpr int WS_GN     = 198144;   // N*3 (atomic)
constexpr int WS_PREDS  = 236544;   // N*3
constexpr int WS_BSUM   = 274944;   // B*3 (atomic)
constexpr int WS_CENTER = 275328;   // B*3 (atomic)
constexpr int WS_MINMAX = 275712;   // 6   (max x3, min x3)
// bf16 fragment-tiled weights (stored as ushort), float-index base:
constexpr int WS_W0T_F  = 276000;   // ushort[512*128]  (= 32768 floats)
constexpr int WS_W1T_F  = 308768;   // ushort[512*512]  (= 131072 floats)
}

typedef short bf16x8 __attribute__((ext_vector_type(8)));
typedef float f32x4 __attribute__((ext_vector_type(4)));

static __device__ __forceinline__ unsigned short f2bf(float f) {
  unsigned int u = __float_as_uint(f);
  unsigned int r = (u + 0x7fffu + ((u >> 16) & 1u)) >> 16;
  return (unsigned short)r;
}
// single-instruction packed f32->bf16 pair: low16 = bf16(a), high16 = bf16(b)
static __device__ __forceinline__ unsigned int pk2bf(float a, float b) {
  unsigned int r;
  asm("v_cvt_pk_bf16_f32 %0, %1, %2" : "=v"(r) : "v"(a), "v"(b));
  return r;
}
static __device__ __forceinline__ float fastrcp(float x) {
  return __builtin_amdgcn_rcpf(x);
}

static __device__ __forceinline__ void atomicMaxFloat(float* addr, float val) {
  int* ai = reinterpret_cast<int*>(addr);
  int old = *ai;
  while (__int_as_float(old) < val) {
    int assumed = old;
    old = atomicCAS(ai, assumed, __float_as_int(val));
    if (old == assumed) break;
  }
}
static __device__ __forceinline__ void atomicMinFloat(float* addr, float val) {
  int* ai = reinterpret_cast<int*>(addr);
  int old = *ai;
  while (__int_as_float(old) > val) {
    int assumed = old;
    old = atomicCAS(ai, assumed, __float_as_int(val));
    if (old == assumed) break;
  }
}

// ---------------- fused prologue: all mutually-independent prep work ----------------
__global__ __launch_bounds__(256) void k_pre(
    const float* lengths, const float* angles, const float* sigmas, const int* tsteps,
    const float* aemb, const float* bbW, const float* rbfW, const float* rbfb,
    const float* bbb, const float* latents, const float* scW0, const float* scb0,
    const float* scW1, unsigned short* w0t, unsigned short* w1t, float* ws) {
  const int blk = blockIdx.x, t = threadIdx.x;
  if (blk < 304) {
    int gid = blk * 256 + t;
    if (gid < 2 * Nn * 3) ws[WS_SN + gid] = 0.f;
    else if (gid < 2 * Nn * 3 + 2 * Bb * 3) ws[WS_BSUM + (gid - 2 * Nn * 3)] = 0.f;
    else if (gid < 2 * Nn * 3 + 2 * Bb * 3 + 3) ws[WS_MINMAX + (gid - 2 * Nn * 3 - 2 * Bb * 3)] = -3.0e38f;
    else if (gid < 2 * Nn * 3 + 2 * Bb * 3 + 6) ws[WS_MINMAX + (gid - 2 * Nn * 3 - 2 * Bb * 3)] = 3.0e38f;
  } else if (blk == 304) {
    int b = t;
    if (b >= Bb) return;
    float a = lengths[b * 3 + 0], bl = lengths[b * 3 + 1], c = lengths[b * 3 + 2];
    const float d2r = 0.017453292519943295f;
    float al = angles[b * 3 + 0] * d2r, be = angles[b * 3 + 1] * d2r, ga = angles[b * 3 + 2] * d2r;
    float ca = cosf(al), cb = cosf(be), cg = cosf(ga), sa = sinf(al), sb = sinf(be);
    float val = (ca * cb - cg) / (sa * sb);
    val = fminf(1.f, fmaxf(-1.f, val));
    float gs = acosf(val);
    float L[3][3];
    L[0][0] = a * sb;              L[0][1] = 0.f;                L[0][2] = a * cb;
    L[1][0] = -bl * sa * cosf(gs); L[1][1] = bl * sa * sinf(gs); L[1][2] = bl * ca;
    L[2][0] = 0.f;                 L[2][1] = 0.f;                L[2][2] = c;
    float det = L[0][0] * (L[1][1] * L[2][2] - L[1][2] * L[2][1])
              - L[0][1] * (L[1][0] * L[2][2] - L[1][2] * L[2][0])
              + L[0][2] * (L[1][0] * L[2][1] - L[1][1] * L[2][0]);
    float id = 1.f / det;
    float inv[3][3];
    inv[0][0] =  (L[1][1]*L[2][2] - L[1][2]*L[2][1]) * id;
    inv[0][1] = -(L[0][1]*L[2][2] - L[0][2]*L[2][1]) * id;
    inv[0][2] =  (L[0][1]*L[1][2] - L[0][2]*L[1][1]) * id;
    inv[1][0] = -(L[1][0]*L[2][2] - L[1][2]*L[2][0]) * id;
    inv[1][1] =  (L[0][0]*L[2][2] - L[0][2]*L[2][0]) * id;
    inv[1][2] = -(L[0][0]*L[1][2] - L[0][2]*L[1][0]) * id;
    inv[2][0] =  (L[1][0]*L[2][1] - L[1][1]*L[2][0]) * id;
    inv[2][1] = -(L[0][0]*L[2][1] - L[0][1]*L[2][0]) * id;
    inv[2][2] =  (L[0][0]*L[1][1] - L[0][1]*L[1][0]) * id;
    for (int i = 0; i < 3; ++i)
      for (int j = 0; j < 3; ++j) {
        ws[WS_L + b * 9 + i * 3 + j] = L[i][j];
        ws[WS_LI + b * 9 + i * 3 + j] = inv[i][j];
      }
    ws[WS_SIG + b] = sigmas[tsteps[b]];
  } else if (blk < 405) {
    int tile = blk - 305;
    if (t < HID) {
      float acc = 0.f;
      for (int k = 0; k < HID; ++k) acc += aemb[tile * HID + k] * bbW[k * HID + t];
      ws[WS_HB + tile * HID + t] = acc;
    }
  } else if (blk == 405) {
    if (t < HID) {
      float accs[NRBF];
#pragma unroll
      for (int k = 0; k < NRBF; ++k) accs[k] = 0.f;
      float accb = 0.f;
      for (int m = 0; m < HID; ++m) {
        float w = bbW[m * HID + t];
#pragma unroll
        for (int k = 0; k < NRBF; ++k) accs[k] += rbfW[k * HID + m] * w;
        accb += rbfb[m] * w;
      }
#pragma unroll
      for (int k = 0; k < NRBF; ++k) ws[WS_RBFW2 + k * HID + t] = accs[k];
      ws[WS_CVEC + t] = accb + bbb[t];
    }
  } else if (blk < 534) {
    int b = blk - 406;
    __shared__ float lat[LAT];
    lat[t] = latents[b * LAT + t];
    __syncthreads();
    int c0 = 2 * t;
    float a0 = 0.f, a1 = 0.f;
    for (int m = 0; m < LAT; ++m) {
      float2 w = *reinterpret_cast<const float2*>(scW0 + (HID + m) * FCH + c0);
      float lm = lat[m];
      a0 += lm * w.x;
      a1 += lm * w.y;
    }
    ws[WS_LATP + b * FCH + c0] = a0 + scb0[c0];
    ws[WS_LATP + b * FCH + c0 + 1] = a1 + scb0[c0 + 1];
  } else if (blk < 790) {
    // cvtW0: coalesced read scW0[tid] (tid = k*512+col, k<128), scattered 2B write
    int tid = (blk - 534) * 256 + t;   // 65536
    int col = tid & 511, k = tid >> 9;
    int id = (((col >> 4) * 4 + (k >> 5)) * 64 + ((k & 31) >> 3) * 16 + (col & 15)) * 8 + (k & 7);
    w0t[id] = f2bf(scW0[tid]);
  } else {
    // cvtW1: coalesced read scW1[tid] (tid = k*512+col, k<512), scattered 2B write
    int tid = (blk - 790) * 256 + t;   // 262144
    int col = tid & 511, k = tid >> 9;
    int id = (((col >> 4) * 16 + (k >> 5)) * 64 + ((k & 31) >> 3) * 16 + (col & 15)) * 8 + (k & 7);
    w1t[id] = f2bf(scW1[tid]);
  }
}

// ---------------- per-node geometry ----------------
__global__ void k_node(const float* frac, const float* noise, const int* batch, float* ws) {
  int n = blockIdx.x * blockDim.x + threadIdx.x;
  if (n >= Nn) return;
  int b = batch[n];
  float L[9], Li[9];
#pragma unroll
  for (int i = 0; i < 9; ++i) { L[i] = ws[WS_L + b * 9 + i]; Li[i] = ws[WS_LI + b * 9 + i]; }
  float f0 = frac[n * 3], f1 = frac[n * 3 + 1], f2 = frac[n * 3 + 2];
  float cg[3], p0[3], fp[3], pe[3], fg[3], fd[3];
#pragma unroll
  for (int j = 0; j < 3; ++j) cg[j] = f0 * L[j] + f1 * L[3 + j] + f2 * L[6 + j];
  float sig = ws[WS_SIG + b];
#pragma unroll
  for (int j = 0; j < 3; ++j) p0[j] = cg[j] + sig * noise[n * 3 + j];
#pragma unroll
  for (int j = 0; j < 3; ++j) {
    float v = p0[0] * Li[j] + p0[1] * Li[3 + j] + p0[2] * Li[6 + j];
    fp[j] = v - floorf(v);
  }
#pragma unroll
  for (int j = 0; j < 3; ++j) pe[j] = fp[0] * L[j] + fp[1] * L[3 + j] + fp[2] * L[6 + j];
#pragma unroll
  for (int j = 0; j < 3; ++j) fg[j] = cg[0] * Li[j] + cg[1] * Li[3 + j] + cg[2] * Li[6 + j];
#pragma unroll
  for (int j = 0; j < 3; ++j) { float d = fg[j] - fp[j]; fd[j] = d - rintf(d); }
#pragma unroll
  for (int j = 0; j < 3; ++j) {
    ws[WS_PERT + n * 3 + j] = pe[j];
    ws[WS_ALIGN + n * 3 + j] = pe[j] + fd[0] * L[j] + fd[1] * L[3 + j] + fd[2] * L[6 + j];
  }
}

// ---------------- the big fused MFMA edge kernel (transposed compute) ----------------
// D[wcol][edge] = mfma(A = W^T fragment, B = act^T fragment); weight tiles in
// ws are direct A-fragments. Activations in LDS in B-fragment tile order at
// TSTRIDE=1040-byte tile stride (16B pad per tile de-aliases the 256-B bank
// pattern of B-frag writes). Every ds_read is lane*16B contiguous.
// Tile: 64 edges x 512 cols, 8 waves; wave wv owns wcols [wv*64, wv*64+64).
// LDS ~70.9 KB -> 2 blocks/CU. Alias plan inside s_hh (64 tiles x 1040 = 66560 B):
//   s_efT  tiles 0..15   bytes [0, 16640)
//   rbfw2  bytes [16640, 24832)  f32[16][128]
//   cvec   bytes [24832, 25344)  f32[128]
//   rbfE   bytes [25344, 29440)  f32[64][16]
// all dead before the GEMM1 epilogue overwrites tiles 0..63 (barrier-enforced).
__global__ __launch_bounds__(512, 4) void k_edge(
    const int* ei, const int* toj, const int* batch, const int* atype,
    const unsigned short* w0t, const unsigned short* w1t,
    const float* scb1, const float* scW2, const float* scb2, float* ws) {
  __shared__ __align__(16) char s_hh_b[64 * TSTRIDE];  // 66560 B
  __shared__ float s_dvec[TE][3];
  __shared__ float s_dist[TE], s_gtd[TE];
  __shared__ int s_tj[TE], s_ti[TE];
  __shared__ float s_wsum[8][TE];             // 2 KB

  char* s_ef_b = s_hh_b;                           // tiles 0..15
  float* s_rbfw2 = (float*)(s_hh_b + 16640);       // [16][128] f32 (8 KB)
  float* s_cvec  = (float*)(s_hh_b + 24832);       // [128] f32 (512 B)
  float* s_rbfE  = (float*)(s_hh_b + 25344);       // [64][16] f32 (4 KB)

  const int t = threadIdx.x;
  const int e0 = blockIdx.x * TE;
  const int b0 = batch[ei[e0]];

  // ---- Phase A: stage rbfW2+cvec to LDS; per-edge geometry + rbf (t<64)
  {
    const float4* src = (const float4*)(ws + WS_RBFW2);  // 512 float4
    float4* dst = (float4*)s_rbfw2;
    dst[t] = src[t];
    if (t < 32) ((float4*)s_cvec)[t] = ((const float4*)(ws + WS_CVEC))[t];
  }
  if (t < TE) {
    int e = e0 + t;
    int jn = ei[e], iN = ei[Ee + e];
    int b = batch[jn];
    float tx = (float)toj[e * 3], ty = (float)toj[e * 3 + 1], tz = (float)toj[e * 3 + 2];
    const float* L = ws + WS_L + b * 9;
    float dv[3], gv[3];
#pragma unroll
    for (int j = 0; j < 3; ++j) {
      float off = tx * L[j] + ty * L[3 + j] + tz * L[6 + j];
      dv[j] = ws[WS_PERT + iN * 3 + j] - ws[WS_PERT + jn * 3 + j] - off;
      gv[j] = ws[WS_ALIGN + iN * 3 + j] - ws[WS_ALIGN + jn * 3 + j] - off;
    }
    float dist = sqrtf(dv[0] * dv[0] + dv[1] * dv[1] + dv[2] * dv[2]);
    float gtd = sqrtf(gv[0] * gv[0] + gv[1] * gv[1] + gv[2] * gv[2]);
#pragma unroll
    for (int j = 0; j < 3; ++j) s_dvec[t][j] = dv[j];
    s_dist[t] = dist;
    s_gtd[t] = gtd;
    s_tj[t] = atype[jn]; s_ti[t] = atype[iN];
    const float step = 7.0f / 15.0f;
#pragma unroll
    for (int k = 0; k < NRBF; ++k) {
      float d = dist - (float)k * step;
      s_rbfE[t * NRBF + k] = __expf(-10.f * d * d);
    }
  }
  __syncthreads();

  // ---- Phase B: ef = silu(hb[tj]+hb[ti]+rbf@rbfW2+cvec) -> s_efT (B-frag tiles)
  {
    int e = t >> 3;              // 0..63 (edge in tile)
    int c0 = (t & 7) * 16;       // 16 hid cols per thread
    int tj = s_tj[e], ti = s_ti[e];
    float4 rb4[4];
#pragma unroll
    for (int q = 0; q < 4; ++q) rb4[q] = ((const float4*)(s_rbfE + e * NRBF))[q];
    float rb[NRBF] = {rb4[0].x, rb4[0].y, rb4[0].z, rb4[0].w,
                      rb4[1].x, rb4[1].y, rb4[1].z, rb4[1].w,
                      rb4[2].x, rb4[2].y, rb4[2].z, rb4[2].w,
                      rb4[3].x, rb4[3].y, rb4[3].z, rb4[3].w};
    float4 z4[4];
#pragma unroll
    for (int q = 0; q < 4; ++q) {
      float4 a = *(const float4*)(ws + WS_HB + tj * HID + c0 + q * 4);
      float4 bq = *(const float4*)(ws + WS_HB + ti * HID + c0 + q * 4);
      float4 cv = ((const float4*)s_cvec)[c0 / 4 + q];
      z4[q].x = a.x + bq.x + cv.x; z4[q].y = a.y + bq.y + cv.y;
      z4[q].z = a.z + bq.z + cv.z; z4[q].w = a.w + bq.w + cv.w;
    }
#pragma unroll
    for (int k = 0; k < NRBF; ++k) {
      float rbk = rb[k];
#pragma unroll
      for (int q = 0; q < 4; ++q) {
        float4 wv4 = ((const float4*)s_rbfw2)[k * 32 + c0 / 4 + q];
        z4[q].x += rbk * wv4.x; z4[q].y += rbk * wv4.y;
        z4[q].z += rbk * wv4.z; z4[q].w += rbk * wv4.w;
      }
    }
    float sv[16];
#pragma unroll
    for (int q = 0; q < 4; ++q) {
      sv[q * 4 + 0] = z4[q].x * fastrcp(1.f + __expf(-z4[q].x));
      sv[q * 4 + 1] = z4[q].y * fastrcp(1.f + __expf(-z4[q].y));
      sv[q * 4 + 2] = z4[q].z * fastrcp(1.f + __expf(-z4[q].z));
      sv[q * 4 + 3] = z4[q].w * fastrcp(1.f + __expf(-z4[q].w));
    }
    unsigned int w[8];
#pragma unroll
    for (int p = 0; p < 8; ++p) w[p] = pk2bf(sv[2 * p], sv[2 * p + 1]);
    // Two 16B stores, one per hid-octet o: hid = c0 + 8o .. c0 + 8o + 7
    int eT = e >> 4, el = e & 15;
#pragma unroll
    for (int o = 0; o < 2; ++o) {
      int hid = c0 + 8 * o;
      int kt = hid >> 5;
      int oct = (hid & 31) >> 3;
      int addr = (kt * 4 + eT) * TSTRIDE + (el + 16 * oct) * 16;
      uint4 val = {w[4 * o + 0], w[4 * o + 1], w[4 * o + 2], w[4 * o + 3]};
      *(uint4*)(s_ef_b + addr) = val;
    }
  }
  __syncthreads();

  const int lane = t & 63;
  const int wv = t >> 6;        // 0..7
  const int el = lane & 15;     // edge-in-tile (D col / B-frag edge)
  const int q  = lane >> 4;     // k-octet group

  // ---- Phase C: GEMM1^T  hh^T = relu(W0a^T @ ef^T + latp), -> s_hhT (B-frag tiles)
  {
    f32x4 acc[4][4];  // [m = wcolTile][n = edgeTile]
#pragma unroll
    for (int m = 0; m < 4; ++m)
#pragma unroll
      for (int n = 0; n < 4; ++n) acc[m][n] = (f32x4){0.f, 0.f, 0.f, 0.f};
    const unsigned short* w0base = w0t + (size_t)(wv * 4) * 4 * 512 + lane * 8;
#pragma unroll
    for (int kt = 0; kt < 4; ++kt) {
      bf16x8 aw[4];
#pragma unroll
      for (int m = 0; m < 4; ++m)
        aw[m] = *(const bf16x8*)(w0base + (size_t)(m * 4 + kt) * 512);
      bf16x8 bf[4];
#pragma unroll
      for (int n = 0; n < 4; ++n)
        bf[n] = *(const bf16x8*)(s_ef_b + (kt * 4 + n) * TSTRIDE + lane * 16);
      __builtin_amdgcn_s_setprio(1);
#pragma unroll
      for (int n = 0; n < 4; ++n)
#pragma unroll
        for (int m = 0; m < 4; ++m)
          acc[m][n] = __builtin_amdgcn_mfma_f32_16x16x32_bf16(aw[m], bf[n], acc[m][n], 0, 0, 0);
      __builtin_amdgcn_s_setprio(0);
    }
    __syncthreads();   // ALL s_efT reads complete before s_hhT overwrites the alias
    // Epilogue: lane holds D[wcol = m*16 + q*4 + r][edge = n*16 + el].
    // Write as GEMM2 B-frag: kTile = wcol>>5, lane' = el + 16*((wcol&31)>>3),
    // thread's r=0..3 are 4 consecutive bf16 = one 8B chunk.
#pragma unroll
    for (int m = 0; m < 4; ++m) {
      float4 lp = *(const float4*)(ws + WS_LATP + b0 * FCH + wv * 64 + m * 16 + q * 4);
#pragma unroll
      for (int n = 0; n < 4; ++n) {
        f32x4 v = acc[m][n];
        float h0 = fmaxf(v[0] + lp.x, 0.f);
        float h1 = fmaxf(v[1] + lp.y, 0.f);
        float h2 = fmaxf(v[2] + lp.z, 0.f);
        float h3 = fmaxf(v[3] + lp.w, 0.f);
        uint2 val = {pk2bf(h0, h1), pk2bf(h2, h3)};
        int kT = wv * 2 + (m >> 1);
        int oct = (m & 1) * 2 + (q >> 1);
        int addr = (kT * 4 + n) * TSTRIDE + (el + 16 * oct) * 16 + (q & 1) * 8;
        *(uint2*)(s_hh_b + addr) = val;
      }
    }
  }
  __syncthreads();

  // ---- Phase D: GEMM2^T + fused score reduction
  {
    f32x4 acc[4][4];  // [m = w1colTile][n = edgeTile]
#pragma unroll
    for (int m = 0; m < 4; ++m)
#pragma unroll
      for (int n = 0; n < 4; ++n) acc[m][n] = (f32x4){0.f, 0.f, 0.f, 0.f};
    const unsigned short* w1base = w1t + (size_t)(wv * 4) * 16 * 512 + lane * 8;
#pragma unroll 4
    for (int kt = 0; kt < 16; ++kt) {
      bf16x8 aw[4];
#pragma unroll
      for (int m = 0; m < 4; ++m)
        aw[m] = *(const bf16x8*)(w1base + (size_t)(m * 16 + kt) * 512);
      bf16x8 bf[4];
#pragma unroll
      for (int n = 0; n < 4; ++n)
        bf[n] = *(const bf16x8*)(s_hh_b + (kt * 4 + n) * TSTRIDE + lane * 16);
      __builtin_amdgcn_s_setprio(1);
#pragma unroll
      for (int n = 0; n < 4; ++n)
#pragma unroll
        for (int m = 0; m < 4; ++m)
          acc[m][n] = __builtin_amdgcn_mfma_f32_16x16x32_bf16(aw[m], bf[n], acc[m][n], 0, 0, 0);
      __builtin_amdgcn_s_setprio(0);
    }
    // hh1 = relu(acc + b1); p[edge] += hh1 * W2, reduced over w1cols
    float p[4] = {0.f, 0.f, 0.f, 0.f};   // per edgeTile n
#pragma unroll
    for (int m = 0; m < 4; ++m) {
      int colb = wv * 64 + m * 16 + q * 4;
      float4 b1v = *(const float4*)(scb1 + colb);
      float4 w2v = *(const float4*)(scW2 + colb);
#pragma unroll
      for (int n = 0; n < 4; ++n) {
        f32x4 v = acc[m][n];
        p[n] += fmaxf(v[0] + b1v.x, 0.f) * w2v.x;
        p[n] += fmaxf(v[1] + b1v.y, 0.f) * w2v.y;
        p[n] += fmaxf(v[2] + b1v.z, 0.f) * w2v.z;
        p[n] += fmaxf(v[3] + b1v.w, 0.f) * w2v.w;
      }
    }
    // reduce over q (lane bits 4..5)
#pragma unroll
    for (int n = 0; n < 4; ++n) {
      float x = p[n];
      x += __shfl_xor(x, 16);
      x += __shfl_xor(x, 32);
      p[n] = x;
    }
    if (lane < 16) {
#pragma unroll
      for (int n = 0; n < 4; ++n) s_wsum[wv][n * 16 + el] = p[n];
    }
  }
  __syncthreads();

  // ---- Phase E: segment-mean scatter (threads 0..63)
  if (t < TE) {
    int e = e0 + t;
    float score = scb2[0];
#pragma unroll
    for (int w = 0; w < 8; ++w) score += s_wsum[w][t];
    int jn = ei[e], iN = ei[Ee + e];
    int s = e;
    while (s > 0 && ei[s - 1] == jn && ei[Ee + s - 1] == iN) --s;
    int en = e;
    while (en + 1 < Ee && ei[en + 1] == jn && ei[Ee + en + 1] == iN) ++en;
    float invc = fastrcp((float)(en - s + 1));
    float dist = s_dist[t];
    float rden = fastrcp(dist + 1e-8f);
    float gts = s_gtd[t] - dist;
#pragma unroll
    for (int j = 0; j < 3; ++j) {
      float dir = s_dvec[t][j] * rden;
      atomicAdd(&ws[WS_SN + iN * 3 + j], score * dir * invc);
      atomicAdd(&ws[WS_GN + iN * 3 + j], gts * dir * invc);
    }
  }
}

// ---------------- per-node: loss terms, preds, center sums ----------------
__global__ void k_node2(const int* batch, float* ws) {
  int n = blockIdx.x * blockDim.x + threadIdx.x;
  if (n >= Nn) return;
  int b = batch[n];
  float sig = ws[WS_SIG + b];
#pragma unroll
  for (int j = 0; j < 3; ++j) {
    float s = ws[WS_SN + n * 3 + j], g = ws[WS_GN + n * 3 + j];
    float d = s - g / sig;
    atomicAdd(&ws[WS_BSUM + b * 3 + j], d * d);
    float pr = ws[WS_PERT + n * 3 + j] + s / sig;
    ws[WS_PREDS + n * 3 + j] = pr;
    atomicAdd(&ws[WS_CENTER + b * 3 + j], pr);
  }
}

// ---------------- per-node: global min/max of dc ----------------
__global__ void k_minmax(const int* batch, const int* num_atoms, float* ws) {
  int n = blockIdx.x * blockDim.x + threadIdx.x;
  int lane = threadIdx.x & 63, wid = threadIdx.x >> 6;
  float mx[3], mn[3];
  if (n < Nn) {
    int b = batch[n];
    float na = (float)num_atoms[b];
#pragma unroll
    for (int j = 0; j < 3; ++j) {
      float v = ws[WS_PREDS + n * 3 + j] - ws[WS_CENTER + b * 3 + j] / na;
      mx[j] = v; mn[j] = v;
    }
  } else {
#pragma unroll
    for (int j = 0; j < 3; ++j) { mx[j] = -3.0e38f; mn[j] = 3.0e38f; }
  }
#pragma unroll
  for (int off = 32; off >= 1; off >>= 1) {
#pragma unroll
    for (int j = 0; j < 3; ++j) {
      mx[j] = fmaxf(mx[j], __shfl_xor(mx[j], off));
      mn[j] = fminf(mn[j], __shfl_xor(mn[j], off));
    }
  }
  __shared__ float smx[4][3], smn[4][3];
  if (lane == 0) {
#pragma unroll
    for (int j = 0; j < 3; ++j) { smx[wid][j] = mx[j]; smn[wid][j] = mn[j]; }
  }
  __syncthreads();
  if (threadIdx.x == 0) {
#pragma unroll
    for (int j = 0; j < 3; ++j) {
      float M = fmaxf(fmaxf(smx[0][j], smx[1][j]), fmaxf(smx[2][j], smx[3][j]));
      float m = fminf(fminf(smn[0][j], smn[1][j]), fminf(smn[2][j], smn[3][j]));
      atomicMaxFloat(&ws[WS_MINMAX + j], M);
      atomicMinFloat(&ws[WS_MINMAX + 3 + j], m);
    }
  }
}

// ---------------- finalize (parallel over batches) ----------------
__global__ void k_final(const int* num_atoms, const float* ws, float* out) {
  int t = threadIdx.x;  // 128 threads
  float loss = 0.f;
  if (t < Bb) {
    float na = (float)num_atoms[t];
    loss = (ws[WS_BSUM + t * 3] + ws[WS_BSUM + t * 3 + 1] + ws[WS_BSUM + t * 3 + 2]) / na;
  }
#pragma unroll
  for (int off = 32; off >= 1; off >>= 1) loss += __shfl_xor(loss, off);
  __shared__ float s2[2];
  if ((t & 63) == 0) s2[t >> 6] = loss;
  __syncthreads();
  if (t == 0) {
    float L = (s2[0] + s2[1]) / (3.0f * (float)Bb);
    float pbs = fabsf(ws[WS_MINMAX + 0] + ws[WS_MINMAX + 3]) +
                fabsf(ws[WS_MINMAX + 1] + ws[WS_MINMAX + 4]) +
                fabsf(ws[WS_MINMAX + 2] + ws[WS_MINMAX + 5]);
    out[0] = L;
    out[1] = pbs;
  }
}

extern "C" void kernel_launch(void* const* d_in, const int* in_sizes, int n_in,
                              void* d_out, int out_size, void* d_ws, size_t ws_size,
                              hipStream_t stream) {
  const float* latents = (const float*)d_in[0];
  const float* gtf     = (const float*)d_in[1];
  const float* lengths = (const float*)d_in[2];
  const float* angles  = (const float*)d_in[3];
  const float* noise   = (const float*)d_in[4];
  const float* sigmas  = (const float*)d_in[5];
  const float* aemb    = (const float*)d_in[6];
  const float* rbfW    = (const float*)d_in[7];
  const float* rbfb    = (const float*)d_in[8];
  const float* bbW     = (const float*)d_in[9];
  const float* bbb     = (const float*)d_in[10];
  const float* scW0    = (const float*)d_in[11];
  const float* scb0    = (const float*)d_in[12];
  const float* scW1    = (const float*)d_in[13];
  const float* scb1    = (const float*)d_in[14];
  const float* scW2    = (const float*)d_in[15];
  const float* scb2    = (const float*)d_in[16];
  const int* num_atoms = (const int*)d_in[17];
  const int* atype     = (const int*)d_in[18];
  const int* batch     = (const int*)d_in[19];
  const int* ei        = (const int*)d_in[20];
  const int* toj       = (const int*)d_in[21];
  const int* tsteps    = (const int*)d_in[22];
  float* ws = (float*)d_ws;
  float* out = (float*)d_out;
  unsigned short* w0t = (unsigned short*)(ws + WS_W0T_F);
  unsigned short* w1t = (unsigned short*)(ws + WS_W1T_F);

  hipLaunchKernelGGL(k_pre, dim3(1814), dim3(256), 0, stream,
                     lengths, angles, sigmas, tsteps, aemb, bbW, rbfW, rbfb, bbb,
                     latents, scW0, scb0, scW1, w0t, w1t, ws);
  hipLaunchKernelGGL(k_node, dim3(50), dim3(256), 0, stream, gtf, noise, batch, ws);
  hipLaunchKernelGGL(k_edge, dim3(Ee / TE), dim3(512), 0, stream,
                     ei, toj, batch, atype, w0t, w1t, scb1, scW2, scb2, ws);
  hipLaunchKernelGGL(k_node2, dim3(50), dim3(256), 0, stream, batch, ws);
  hipLaunchKernelGGL(k_minmax, dim3(50), dim3(256), 0, stream, batch, num_atoms, ws);
  hipLaunchKernelGGL(k_final, dim3(1), dim3(128), 0, stream, num_atoms, ws, out);
}